// Round 1
// baseline (6510.509 us; speedup 1.0000x reference)
//
#include <hip/hip_runtime.h>

#define HDIM 128
#define NGRAPH 64
#define INVSTD 0.99999500003749972f   // 1/sqrt(1+1e-5)

// ---------------- encode: h[n][k] = x[n]*ew[k] + eb[k] ----------------
__global__ void k_encode(const float* __restrict__ x, const float* __restrict__ ew,
                         const float* __restrict__ eb, float* __restrict__ h, int N) {
    int tid = blockIdx.x * blockDim.x + threadIdx.x;
    int stride = gridDim.x * blockDim.x;
    int q = tid & 31;                       // constant per thread (stride % 32 == 0)
    float4 w4 = ((const float4*)ew)[q];
    float4 b4 = ((const float4*)eb)[q];
    int total = N * 32;
    for (int t = tid; t < total; t += stride) {
        int n = t >> 5;
        float xv = x[n];
        float4 r;
        r.x = fmaf(xv, w4.x, b4.x);
        r.y = fmaf(xv, w4.y, b4.y);
        r.z = fmaf(xv, w4.z, b4.z);
        r.w = fmaf(xv, w4.w, b4.w);
        ((float4*)(h + (size_t)n * HDIM))[q] = r;
    }
}

// ------------- edge kernel: agg[dst] += relu(h[src] + attr*ew + eb) -------------
__global__ void k_edge(const float* __restrict__ h, const int* __restrict__ ei,
                       const float* __restrict__ attr,
                       const float* __restrict__ ew, const float* __restrict__ eb,
                       float* agg, int E) {
    int tid = blockIdx.x * blockDim.x + threadIdx.x;
    int stride = gridDim.x * blockDim.x;
    int q = tid & 31;
    float4 w4 = ((const float4*)ew)[q];
    float4 b4 = ((const float4*)eb)[q];
    int total = E * 32;
    for (int t = tid; t < total; t += stride) {
        int e = t >> 5;
        int s = ei[e];
        int d = ei[E + e];
        float a = attr[e];
        float4 hv = *(const float4*)(h + (size_t)s * HDIM + q * 4);
        float4 m;
        m.x = fmaxf(hv.x + fmaf(a, w4.x, b4.x), 0.f);
        m.y = fmaxf(hv.y + fmaf(a, w4.y, b4.y), 0.f);
        m.z = fmaxf(hv.z + fmaf(a, w4.z, b4.z), 0.f);
        m.w = fmaxf(hv.w + fmaf(a, w4.w, b4.w), 0.f);
        float* ap = agg + (size_t)d * HDIM + q * 4;
        atomicAdd(ap + 0, m.x);
        atomicAdd(ap + 1, m.y);
        atomicAdd(ap + 2, m.z);
        atomicAdd(ap + 3, m.w);
    }
}

// ------------- fused MLP half: out = epilogue(Z @ W + bias) -------------
// mode 0: Z = (1+eps)*A + Agg, epilogue = relu                     (GEMM1 -> t)
// mode 1: Z = A,               epilogue = relu(gamma*v*INVSTD+beta) (GEMM2 -> h)
#define GROWS 128
__global__ __launch_bounds__(512, 1) void k_mlp(
    const float* A, const float* Agg, const float* __restrict__ epsp,
    const float* __restrict__ W, const float* __restrict__ bias,
    const float* __restrict__ gam, const float* __restrict__ bet,
    float* outp, int N, int mode) {
    __shared__ float zs[GROWS][129];
    __shared__ float wsm[128 * 128];
    int tid = threadIdx.x;
    int row0 = blockIdx.x * GROWS;

    // stage W (row-major [k][j])
    #pragma unroll
    for (int i = 0; i < 8; ++i) {
        int c = tid + i * 512;
        ((float4*)wsm)[c] = ((const float4*)W)[c];
    }
    // stage Z
    float scale = (mode == 0) ? (1.f + epsp[0]) : 0.f;
    #pragma unroll
    for (int i = 0; i < 8; ++i) {
        int c = tid + i * 512;          // c in [0, 4096)
        int r = c >> 5, k4 = c & 31;
        int gr = row0 + r;
        float4 z4 = make_float4(0.f, 0.f, 0.f, 0.f);
        if (gr < N) {
            float4 a4 = ((const float4*)(A + (size_t)gr * HDIM))[k4];
            if (mode == 0) {
                float4 g4 = ((const float4*)(Agg + (size_t)gr * HDIM))[k4];
                z4.x = fmaf(scale, a4.x, g4.x);
                z4.y = fmaf(scale, a4.y, g4.y);
                z4.z = fmaf(scale, a4.z, g4.z);
                z4.w = fmaf(scale, a4.w, g4.w);
            } else {
                z4 = a4;
            }
        }
        zs[r][k4 * 4 + 0] = z4.x;
        zs[r][k4 * 4 + 1] = z4.y;
        zs[r][k4 * 4 + 2] = z4.z;
        zs[r][k4 * 4 + 3] = z4.w;
    }
    __syncthreads();

    int cg = tid & 15;        // col group: cols {4cg..4cg+3} U {64+4cg..}
    int rg = tid >> 4;        // row group: rows {rg, rg+32, rg+64, rg+96}
    float acc[4][8];
    #pragma unroll
    for (int i = 0; i < 4; ++i)
        #pragma unroll
        for (int j = 0; j < 8; ++j) acc[i][j] = 0.f;

    #pragma unroll 4
    for (int k = 0; k < 128; ++k) {
        float aa[4];
        aa[0] = zs[rg][k];
        aa[1] = zs[rg + 32][k];
        aa[2] = zs[rg + 64][k];
        aa[3] = zs[rg + 96][k];
        float4 b0 = *(const float4*)&wsm[k * 128 + 4 * cg];
        float4 b1v = *(const float4*)&wsm[k * 128 + 64 + 4 * cg];
        float bb[8] = {b0.x, b0.y, b0.z, b0.w, b1v.x, b1v.y, b1v.z, b1v.w};
        #pragma unroll
        for (int i = 0; i < 4; ++i)
            #pragma unroll
            for (int j = 0; j < 8; ++j)
                acc[i][j] = fmaf(aa[i], bb[j], acc[i][j]);
    }

    // epilogue
    float4 bl = ((const float4*)bias)[cg];
    float4 bh = ((const float4*)bias)[16 + cg];
    float bb_[8] = {bl.x, bl.y, bl.z, bl.w, bh.x, bh.y, bh.z, bh.w};
    float gg[8], tt[8];
    if (mode == 1) {
        float4 gl = ((const float4*)gam)[cg];
        float4 gh = ((const float4*)gam)[16 + cg];
        float4 tl = ((const float4*)bet)[cg];
        float4 th = ((const float4*)bet)[16 + cg];
        gg[0]=gl.x; gg[1]=gl.y; gg[2]=gl.z; gg[3]=gl.w;
        gg[4]=gh.x; gg[5]=gh.y; gg[6]=gh.z; gg[7]=gh.w;
        tt[0]=tl.x; tt[1]=tl.y; tt[2]=tl.z; tt[3]=tl.w;
        tt[4]=th.x; tt[5]=th.y; tt[6]=th.z; tt[7]=th.w;
    }
    #pragma unroll
    for (int i = 0; i < 4; ++i) {
        int gr = row0 + rg + 32 * i;
        if (gr < N) {
            float o[8];
            #pragma unroll
            for (int j = 0; j < 8; ++j) {
                float v = acc[i][j] + bb_[j];
                if (mode == 0) v = fmaxf(v, 0.f);
                else           v = fmaxf(fmaf(gg[j] * v, INVSTD, tt[j]), 0.f);
                o[j] = v;
            }
            *(float4*)(outp + (size_t)gr * HDIM + 4 * cg) = make_float4(o[0], o[1], o[2], o[3]);
            *(float4*)(outp + (size_t)gr * HDIM + 64 + 4 * cg) = make_float4(o[4], o[5], o[6], o[7]);
        }
    }
}

// ------------- pooling: atomics into per-graph sums + counts -------------
__global__ void k_pool(const float* __restrict__ h, const int* __restrict__ batch,
                       float* pooled, float* cnt, int N) {
    int tid = blockIdx.x * blockDim.x + threadIdx.x;
    int stride = gridDim.x * blockDim.x;
    int q = tid & 31;
    int total = N * 32;
    for (int t = tid; t < total; t += stride) {
        int n = t >> 5;
        int g = batch[n];
        float4 hv = ((const float4*)(h + (size_t)n * HDIM))[q];
        float* pp = pooled + g * HDIM + q * 4;
        atomicAdd(pp + 0, hv.x);
        atomicAdd(pp + 1, hv.y);
        atomicAdd(pp + 2, hv.z);
        atomicAdd(pp + 3, hv.w);
        if (q == 0) atomicAdd(cnt + g, 1.0f);
    }
}

// ------------- classifier: out[g] = sigmoid(relu(p@cw1+cb1)@cw2+cb2) -------------
__global__ void k_classify(const float* __restrict__ pooled, const float* __restrict__ cnt,
                           const float* __restrict__ cw1, const float* __restrict__ cb1,
                           const float* __restrict__ cw2, const float* __restrict__ cb2,
                           float* __restrict__ out) {
    __shared__ float p[HDIM];
    int g = blockIdx.x, j = threadIdx.x;   // 64 threads = 1 wave
    float c = fmaxf(cnt[g], 1.f);
    p[j]      = pooled[g * HDIM + j] / c;
    p[j + 64] = pooled[g * HDIM + j + 64] / c;
    __syncthreads();
    float acc = cb1[j];
    #pragma unroll 4
    for (int k = 0; k < HDIM; ++k) acc = fmaf(p[k], cw1[k * 64 + j], acc);
    acc = fmaxf(acc, 0.f);
    float v = acc * cw2[j];
    #pragma unroll
    for (int off = 32; off > 0; off >>= 1) v += __shfl_down(v, off, 64);
    if (j == 0) out[g] = 1.f / (1.f + expf(-(v + cb2[0])));
}

extern "C" void kernel_launch(void* const* d_in, const int* in_sizes, int n_in,
                              void* d_out, int out_size, void* d_ws, size_t ws_size,
                              hipStream_t stream) {
    const float* x      = (const float*)d_in[0];
    const int*   ei     = (const int*)d_in[1];
    const float* eattr  = (const float*)d_in[2];
    const int*   batch  = (const int*)d_in[3];
    const float* enc_w  = (const float*)d_in[4];
    const float* enc_b  = (const float*)d_in[5];
    const float* eenc_w = (const float*)d_in[6];
    const float* eenc_b = (const float*)d_in[7];
    const float* eps    = (const float*)d_in[8];
    const float* w1     = (const float*)d_in[9];
    const float* b1     = (const float*)d_in[10];
    const float* w2     = (const float*)d_in[11];
    const float* b2     = (const float*)d_in[12];
    const float* gamma  = (const float*)d_in[13];
    const float* beta   = (const float*)d_in[14];
    const float* cw1    = (const float*)d_in[15];
    const float* cb1    = (const float*)d_in[16];
    const float* cw2    = (const float*)d_in[17];
    const float* cb2    = (const float*)d_in[18];

    int N = in_sizes[0];          // 100000
    int E = in_sizes[2];          // 1600000

    char* wsb = (char*)d_ws;
    size_t hbytes = (size_t)N * HDIM * sizeof(float);
    float* h      = (float*)wsb;
    float* agg    = (float*)(wsb + hbytes);          // also aliased as t
    float* pooled = (float*)(wsb + 2 * hbytes);
    float* cnt    = pooled + NGRAPH * HDIM;

    hipMemsetAsync(pooled, 0, (NGRAPH * HDIM + NGRAPH) * sizeof(float), stream);
    k_encode<<<2048, 256, 0, stream>>>(x, enc_w, enc_b, h, N);

    int gblocks = (N + GROWS - 1) / GROWS;
    for (int l = 0; l < 2; ++l) {
        hipMemsetAsync(agg, 0, hbytes, stream);
        k_edge<<<2048, 256, 0, stream>>>(h, ei, eattr, eenc_w, eenc_b, agg, E);
        // GEMM1: t = relu(((1+eps)h + agg) @ w1 + b1); t aliases agg (row-local)
        k_mlp<<<gblocks, 512, 0, stream>>>(h, agg, eps + l, w1 + (size_t)l * HDIM * HDIM,
                                           b1 + l * HDIM, nullptr, nullptr, agg, N, 0);
        // GEMM2: h = relu(gamma*((t @ w2 + b2))*INVSTD + beta)
        k_mlp<<<gblocks, 512, 0, stream>>>(agg, nullptr, nullptr, w2 + (size_t)l * HDIM * HDIM,
                                           b2 + l * HDIM, gamma + l * HDIM, beta + l * HDIM, h, N, 1);
    }

    k_pool<<<2048, 256, 0, stream>>>(h, batch, pooled, cnt, N);
    k_classify<<<NGRAPH, 64, 0, stream>>>(pooled, cnt, cw1, cb1, cw2, cb2, (float*)d_out);
}

// Round 2
// 1515.290 us; speedup vs baseline: 4.2965x; 4.2965x over previous
//
#include <hip/hip_runtime.h>

#define HDIM 128
#define NGRAPH 64
#define INVSTD 0.99999500003749972f   // 1/sqrt(1+1e-5)

// ---------------- encode: h[n][k] = x[n]*ew[k] + eb[k] ----------------
__global__ void k_encode(const float* __restrict__ x, const float* __restrict__ ew,
                         const float* __restrict__ eb, float* __restrict__ h, int N) {
    int tid = blockIdx.x * blockDim.x + threadIdx.x;
    int stride = gridDim.x * blockDim.x;
    int q = tid & 31;
    float4 w4 = ((const float4*)ew)[q];
    float4 b4 = ((const float4*)eb)[q];
    int total = N * 32;
    for (int t = tid; t < total; t += stride) {
        int n = t >> 5;
        float xv = x[n];
        float4 r;
        r.x = fmaf(xv, w4.x, b4.x);
        r.y = fmaf(xv, w4.y, b4.y);
        r.z = fmaf(xv, w4.z, b4.z);
        r.w = fmaf(xv, w4.w, b4.w);
        ((float4*)(h + (size_t)n * HDIM))[q] = r;
    }
}

// ---------------- CSR build ----------------
__global__ void k_hist(const int* __restrict__ ei, int* deg, int E) {
    int tid = blockIdx.x * blockDim.x + threadIdx.x;
    int stride = gridDim.x * blockDim.x;
    for (int e = tid; e < E; e += stride) atomicAdd(&deg[ei[E + e]], 1);
}

// per-block exclusive scan; block totals to bsum
__global__ void k_scan1(const int* __restrict__ deg, int* rs, int* bsum, int N) {
    __shared__ int sm[256];
    int gid = blockIdx.x * 256 + threadIdx.x;
    int v = (gid < N) ? deg[gid] : 0;
    sm[threadIdx.x] = v;
    __syncthreads();
    #pragma unroll
    for (int off = 1; off < 256; off <<= 1) {
        int t = (threadIdx.x >= off) ? sm[threadIdx.x - off] : 0;
        __syncthreads();
        sm[threadIdx.x] += t;
        __syncthreads();
    }
    if (gid < N) rs[gid] = sm[threadIdx.x] - v;
    if (threadIdx.x == 255) bsum[blockIdx.x] = sm[255];
}

__global__ void k_scan2(int* bsum, int nb) {
    __shared__ int sm[512];
    int t = threadIdx.x;
    int v = (t < nb) ? bsum[t] : 0;
    sm[t] = v;
    __syncthreads();
    #pragma unroll
    for (int off = 1; off < 512; off <<= 1) {
        int u = (t >= off) ? sm[t - off] : 0;
        __syncthreads();
        sm[t] += u;
        __syncthreads();
    }
    if (t < nb) bsum[t] = sm[t] - v;
}

__global__ void k_scan3(int* rs, const int* __restrict__ bsum, int* cur, int N, int E) {
    int gid = blockIdx.x * 256 + threadIdx.x;
    if (gid < N) {
        int v = rs[gid] + bsum[gid >> 8];
        rs[gid] = v;
        cur[gid] = v;
    }
    if (gid == N) rs[N] = E;
}

__global__ void k_scatter(const int* __restrict__ ei, const float* __restrict__ attr,
                          int* cur, int* es, float* ea, int E) {
    int tid = blockIdx.x * blockDim.x + threadIdx.x;
    int stride = gridDim.x * blockDim.x;
    for (int e = tid; e < E; e += stride) {
        int s = ei[e], d = ei[E + e];
        int p = atomicAdd(&cur[d], 1);
        es[p] = s;
        ea[p] = attr[e];
    }
}

// ------- aggregation: one wave per dst node, no float atomics -------
// z[n] = (1+eps)*h[n] + sum_{e in CSR[n]} relu(h[src_e] + a_e*ew + eb)
__global__ __launch_bounds__(256) void k_agg(
    const float* __restrict__ h, const int* __restrict__ rs,
    const int* __restrict__ es, const float* __restrict__ ea,
    const float* __restrict__ ew, const float* __restrict__ eb,
    const float* __restrict__ epsp, float* __restrict__ z, int N) {
    int wave = (blockIdx.x * 256 + threadIdx.x) >> 6;
    int lane = threadIdx.x & 63;
    int half = lane >> 5, q = lane & 31;
    if (wave >= N) return;
    int n = wave;
    int beg = rs[n], end = rs[n + 1];
    float4 w4 = ((const float4*)ew)[q];
    float4 b4 = ((const float4*)eb)[q];
    float4 acc = make_float4(0.f, 0.f, 0.f, 0.f);
    for (int i = beg + half; i < end; i += 2) {
        int s = es[i];
        float a = ea[i];
        float4 hv = ((const float4*)(h + (size_t)s * HDIM))[q];
        acc.x += fmaxf(hv.x + fmaf(a, w4.x, b4.x), 0.f);
        acc.y += fmaxf(hv.y + fmaf(a, w4.y, b4.y), 0.f);
        acc.z += fmaxf(hv.z + fmaf(a, w4.z, b4.z), 0.f);
        acc.w += fmaxf(hv.w + fmaf(a, w4.w, b4.w), 0.f);
    }
    acc.x += __shfl_xor(acc.x, 32);
    acc.y += __shfl_xor(acc.y, 32);
    acc.z += __shfl_xor(acc.z, 32);
    acc.w += __shfl_xor(acc.w, 32);
    if (half == 0) {
        float sc = 1.f + epsp[0];
        float4 hn = ((const float4*)(h + (size_t)n * HDIM))[q];
        float4 o;
        o.x = fmaf(sc, hn.x, acc.x);
        o.y = fmaf(sc, hn.y, acc.y);
        o.z = fmaf(sc, hn.z, acc.z);
        o.w = fmaf(sc, hn.w, acc.w);
        ((float4*)(z + (size_t)n * HDIM))[q] = o;
    }
}

// ------------- MLP half: out = epilogue(Z @ W + bias) -------------
// mode 0: epilogue = relu; mode 1: epilogue = relu(gamma*v*INVSTD+beta)
#define GROWS 128
__global__ __launch_bounds__(512, 1) void k_mlp(
    const float* __restrict__ A,
    const float* __restrict__ W, const float* __restrict__ bias,
    const float* __restrict__ gam, const float* __restrict__ bet,
    float* outp, int N, int mode) {
    __shared__ float zs[GROWS][129];
    __shared__ float wsm[128 * 128];
    int tid = threadIdx.x;
    int row0 = blockIdx.x * GROWS;

    #pragma unroll
    for (int i = 0; i < 8; ++i) {
        int c = tid + i * 512;
        ((float4*)wsm)[c] = ((const float4*)W)[c];
    }
    #pragma unroll
    for (int i = 0; i < 8; ++i) {
        int c = tid + i * 512;          // [0, 4096)
        int r = c >> 5, k4 = c & 31;
        int gr = row0 + r;
        float4 z4 = make_float4(0.f, 0.f, 0.f, 0.f);
        if (gr < N) z4 = ((const float4*)(A + (size_t)gr * HDIM))[k4];
        zs[r][k4 * 4 + 0] = z4.x;
        zs[r][k4 * 4 + 1] = z4.y;
        zs[r][k4 * 4 + 2] = z4.z;
        zs[r][k4 * 4 + 3] = z4.w;
    }
    __syncthreads();

    int cg = tid & 15;
    int rg = tid >> 4;
    float acc[4][8];
    #pragma unroll
    for (int i = 0; i < 4; ++i)
        #pragma unroll
        for (int j = 0; j < 8; ++j) acc[i][j] = 0.f;

    #pragma unroll 4
    for (int k = 0; k < 128; ++k) {
        float aa[4];
        aa[0] = zs[rg][k];
        aa[1] = zs[rg + 32][k];
        aa[2] = zs[rg + 64][k];
        aa[3] = zs[rg + 96][k];
        float4 b0 = *(const float4*)&wsm[k * 128 + 4 * cg];
        float4 b1v = *(const float4*)&wsm[k * 128 + 64 + 4 * cg];
        float bb[8] = {b0.x, b0.y, b0.z, b0.w, b1v.x, b1v.y, b1v.z, b1v.w};
        #pragma unroll
        for (int i = 0; i < 4; ++i)
            #pragma unroll
            for (int j = 0; j < 8; ++j)
                acc[i][j] = fmaf(aa[i], bb[j], acc[i][j]);
    }

    float4 bl = ((const float4*)bias)[cg];
    float4 bh = ((const float4*)bias)[16 + cg];
    float bb_[8] = {bl.x, bl.y, bl.z, bl.w, bh.x, bh.y, bh.z, bh.w};
    float gg[8], tt[8];
    if (mode == 1) {
        float4 gl = ((const float4*)gam)[cg];
        float4 gh = ((const float4*)gam)[16 + cg];
        float4 tl = ((const float4*)bet)[cg];
        float4 th = ((const float4*)bet)[16 + cg];
        gg[0]=gl.x; gg[1]=gl.y; gg[2]=gl.z; gg[3]=gl.w;
        gg[4]=gh.x; gg[5]=gh.y; gg[6]=gh.z; gg[7]=gh.w;
        tt[0]=tl.x; tt[1]=tl.y; tt[2]=tl.z; tt[3]=tl.w;
        tt[4]=th.x; tt[5]=th.y; tt[6]=th.z; tt[7]=th.w;
    }
    #pragma unroll
    for (int i = 0; i < 4; ++i) {
        int gr = row0 + rg + 32 * i;
        if (gr < N) {
            float o[8];
            #pragma unroll
            for (int j = 0; j < 8; ++j) {
                float v = acc[i][j] + bb_[j];
                if (mode == 0) v = fmaxf(v, 0.f);
                else           v = fmaxf(fmaf(gg[j] * v, INVSTD, tt[j]), 0.f);
                o[j] = v;
            }
            *(float4*)(outp + (size_t)gr * HDIM + 4 * cg) = make_float4(o[0], o[1], o[2], o[3]);
            *(float4*)(outp + (size_t)gr * HDIM + 64 + 4 * cg) = make_float4(o[4], o[5], o[6], o[7]);
        }
    }
}

// ------------- pooling -------------
__global__ void k_pool(const float* __restrict__ h, const int* __restrict__ batch,
                       float* pooled, float* cnt, int N) {
    int tid = blockIdx.x * blockDim.x + threadIdx.x;
    int stride = gridDim.x * blockDim.x;
    int q = tid & 31;
    int total = N * 32;
    for (int t = tid; t < total; t += stride) {
        int n = t >> 5;
        int g = batch[n];
        float4 hv = ((const float4*)(h + (size_t)n * HDIM))[q];
        float* pp = pooled + g * HDIM + q * 4;
        atomicAdd(pp + 0, hv.x);
        atomicAdd(pp + 1, hv.y);
        atomicAdd(pp + 2, hv.z);
        atomicAdd(pp + 3, hv.w);
        if (q == 0) atomicAdd(cnt + g, 1.0f);
    }
}

// ------------- classifier -------------
__global__ void k_classify(const float* __restrict__ pooled, const float* __restrict__ cnt,
                           const float* __restrict__ cw1, const float* __restrict__ cb1,
                           const float* __restrict__ cw2, const float* __restrict__ cb2,
                           float* __restrict__ out) {
    __shared__ float p[HDIM];
    int g = blockIdx.x, j = threadIdx.x;
    float c = fmaxf(cnt[g], 1.f);
    p[j]      = pooled[g * HDIM + j] / c;
    p[j + 64] = pooled[g * HDIM + j + 64] / c;
    __syncthreads();
    float acc = cb1[j];
    #pragma unroll 4
    for (int k = 0; k < HDIM; ++k) acc = fmaf(p[k], cw1[k * 64 + j], acc);
    acc = fmaxf(acc, 0.f);
    float v = acc * cw2[j];
    #pragma unroll
    for (int off = 32; off > 0; off >>= 1) v += __shfl_down(v, off, 64);
    if (j == 0) out[g] = 1.f / (1.f + expf(-(v + cb2[0])));
}

static inline size_t align_up(size_t v, size_t a) { return (v + a - 1) & ~(a - 1); }

extern "C" void kernel_launch(void* const* d_in, const int* in_sizes, int n_in,
                              void* d_out, int out_size, void* d_ws, size_t ws_size,
                              hipStream_t stream) {
    const float* x      = (const float*)d_in[0];
    const int*   ei     = (const int*)d_in[1];
    const float* eattr  = (const float*)d_in[2];
    const int*   batch  = (const int*)d_in[3];
    const float* enc_w  = (const float*)d_in[4];
    const float* enc_b  = (const float*)d_in[5];
    const float* eenc_w = (const float*)d_in[6];
    const float* eenc_b = (const float*)d_in[7];
    const float* eps    = (const float*)d_in[8];
    const float* w1     = (const float*)d_in[9];
    const float* b1     = (const float*)d_in[10];
    const float* w2     = (const float*)d_in[11];
    const float* b2     = (const float*)d_in[12];
    const float* gamma  = (const float*)d_in[13];
    const float* beta   = (const float*)d_in[14];
    const float* cw1    = (const float*)d_in[15];
    const float* cb1    = (const float*)d_in[16];
    const float* cw2    = (const float*)d_in[17];
    const float* cb2    = (const float*)d_in[18];

    int N = in_sizes[0];          // 100000
    int E = in_sizes[2];          // 1600000

    char* wsb = (char*)d_ws;
    size_t off = 0;
    size_t hbytes = (size_t)N * HDIM * sizeof(float);
    float* h      = (float*)(wsb + off); off = align_up(off + hbytes, 256);
    float* z      = (float*)(wsb + off); off = align_up(off + hbytes, 256);   // aliased t
    float* pooled = (float*)(wsb + off); off = align_up(off + NGRAPH * HDIM * 4, 256);
    float* cnt    = (float*)(wsb + off); off = align_up(off + NGRAPH * 4, 256);
    int*   deg    = (int*)(wsb + off);   off = align_up(off + (size_t)N * 4, 256);
    int*   rs     = (int*)(wsb + off);   off = align_up(off + (size_t)(N + 1) * 4, 256);
    int*   cur    = (int*)(wsb + off);   off = align_up(off + (size_t)N * 4, 256);
    int*   bsum   = (int*)(wsb + off);   off = align_up(off + 2048 * 4, 256);
    int*   es     = (int*)(wsb + off);   off = align_up(off + (size_t)E * 4, 256);
    float* ea     = (float*)(wsb + off); off = align_up(off + (size_t)E * 4, 256);

    int nb = (N + 255) / 256;

    // CSR build
    hipMemsetAsync(deg, 0, (size_t)N * 4, stream);
    k_hist<<<2048, 256, 0, stream>>>(ei, deg, E);
    k_scan1<<<nb, 256, 0, stream>>>(deg, rs, bsum, N);
    k_scan2<<<1, 512, 0, stream>>>(bsum, nb);
    k_scan3<<<(N + 256) / 256, 256, 0, stream>>>(rs, bsum, cur, N, E);
    k_scatter<<<2048, 256, 0, stream>>>(ei, eattr, cur, es, ea, E);

    hipMemsetAsync(pooled, 0, (NGRAPH * HDIM + NGRAPH) * sizeof(float), stream);
    k_encode<<<2048, 256, 0, stream>>>(x, enc_w, enc_b, h, N);

    int gblocks = (N + GROWS - 1) / GROWS;
    int ablocks = (N * 64 + 255) / 256;
    for (int l = 0; l < 2; ++l) {
        k_agg<<<ablocks, 256, 0, stream>>>(h, rs, es, ea, eenc_w, eenc_b, eps + l, z, N);
        // GEMM1: z = relu(z @ w1 + b1)   (in-place, block-local rows)
        k_mlp<<<gblocks, 512, 0, stream>>>(z, w1 + (size_t)l * HDIM * HDIM,
                                           b1 + l * HDIM, nullptr, nullptr, z, N, 0);
        // GEMM2: h = relu(gamma*(z @ w2 + b2)*INVSTD + beta)
        k_mlp<<<gblocks, 512, 0, stream>>>(z, w2 + (size_t)l * HDIM * HDIM,
                                           b2 + l * HDIM, gamma + l * HDIM, beta + l * HDIM, h, N, 1);
    }

    k_pool<<<2048, 256, 0, stream>>>(h, batch, pooled, cnt, N);
    k_classify<<<NGRAPH, 64, 0, stream>>>(pooled, cnt, cw1, cb1, cw2, cb2, (float*)d_out);
}

// Round 3
// 759.132 us; speedup vs baseline: 8.5763x; 1.9961x over previous
//
#include <hip/hip_runtime.h>

#define HDIM 128
#define NGRAPH 64
#define INVSTD 0.99999500003749972f   // 1/sqrt(1+1e-5)

// ---------------- encode: h[n][k] = x[n]*ew[k] + eb[k] ----------------
__global__ void k_encode(const float* __restrict__ x, const float* __restrict__ ew,
                         const float* __restrict__ eb, float* __restrict__ h, int N) {
    int tid = blockIdx.x * blockDim.x + threadIdx.x;
    int stride = gridDim.x * blockDim.x;
    int q = tid & 31;
    float4 w4 = ((const float4*)ew)[q];
    float4 b4 = ((const float4*)eb)[q];
    int total = N * 32;
    for (int t = tid; t < total; t += stride) {
        int n = t >> 5;
        float xv = x[n];
        float4 r;
        r.x = fmaf(xv, w4.x, b4.x);
        r.y = fmaf(xv, w4.y, b4.y);
        r.z = fmaf(xv, w4.z, b4.z);
        r.w = fmaf(xv, w4.w, b4.w);
        ((float4*)(h + (size_t)n * HDIM))[q] = r;
    }
}

// ---------------- CSR build ----------------
__global__ void k_hist(const int* __restrict__ ei, int* deg, int E) {
    int tid = blockIdx.x * blockDim.x + threadIdx.x;
    int stride = gridDim.x * blockDim.x;
    for (int e = tid; e < E; e += stride) atomicAdd(&deg[ei[E + e]], 1);
}

__global__ void k_scan1(const int* __restrict__ deg, int* rs, int* bsum, int N) {
    __shared__ int sm[256];
    int gid = blockIdx.x * 256 + threadIdx.x;
    int v = (gid < N) ? deg[gid] : 0;
    sm[threadIdx.x] = v;
    __syncthreads();
    #pragma unroll
    for (int off = 1; off < 256; off <<= 1) {
        int t = (threadIdx.x >= off) ? sm[threadIdx.x - off] : 0;
        __syncthreads();
        sm[threadIdx.x] += t;
        __syncthreads();
    }
    if (gid < N) rs[gid] = sm[threadIdx.x] - v;
    if (threadIdx.x == 255) bsum[blockIdx.x] = sm[255];
}

__global__ void k_scan2(int* bsum, int nb) {
    __shared__ int sm[512];
    int t = threadIdx.x;
    int v = (t < nb) ? bsum[t] : 0;
    sm[t] = v;
    __syncthreads();
    #pragma unroll
    for (int off = 1; off < 512; off <<= 1) {
        int u = (t >= off) ? sm[t - off] : 0;
        __syncthreads();
        sm[t] += u;
        __syncthreads();
    }
    if (t < nb) bsum[t] = sm[t] - v;
}

__global__ void k_scan3(int* rs, const int* __restrict__ bsum, int* cur, int N, int E) {
    int gid = blockIdx.x * 256 + threadIdx.x;
    if (gid < N) {
        int v = rs[gid] + bsum[gid >> 8];
        rs[gid] = v;
        cur[gid] = v;
    }
    if (gid == N) rs[N] = E;
}

__global__ void k_scatter(const int* __restrict__ ei, const float* __restrict__ attr,
                          int* cur, int* es, float* ea, int E) {
    int tid = blockIdx.x * blockDim.x + threadIdx.x;
    int stride = gridDim.x * blockDim.x;
    for (int e = tid; e < E; e += stride) {
        int s = ei[e], d = ei[E + e];
        int p = atomicAdd(&cur[d], 1);
        es[p] = s;
        ea[p] = attr[e];
    }
}

// ------- aggregation: one wave per dst node, no float atomics -------
__global__ __launch_bounds__(256) void k_agg(
    const float* __restrict__ h, const int* __restrict__ rs,
    const int* __restrict__ es, const float* __restrict__ ea,
    const float* __restrict__ ew, const float* __restrict__ eb,
    const float* __restrict__ epsp, float* __restrict__ z, int N) {
    int wave = (blockIdx.x * 256 + threadIdx.x) >> 6;
    int lane = threadIdx.x & 63;
    int half = lane >> 5, q = lane & 31;
    if (wave >= N) return;
    int n = wave;
    int beg = rs[n], end = rs[n + 1];
    float4 w4 = ((const float4*)ew)[q];
    float4 b4 = ((const float4*)eb)[q];
    float4 acc = make_float4(0.f, 0.f, 0.f, 0.f);
    for (int i = beg + half; i < end; i += 2) {
        int s = es[i];
        float a = ea[i];
        float4 hv = ((const float4*)(h + (size_t)s * HDIM))[q];
        acc.x += fmaxf(hv.x + fmaf(a, w4.x, b4.x), 0.f);
        acc.y += fmaxf(hv.y + fmaf(a, w4.y, b4.y), 0.f);
        acc.z += fmaxf(hv.z + fmaf(a, w4.z, b4.z), 0.f);
        acc.w += fmaxf(hv.w + fmaf(a, w4.w, b4.w), 0.f);
    }
    acc.x += __shfl_xor(acc.x, 32);
    acc.y += __shfl_xor(acc.y, 32);
    acc.z += __shfl_xor(acc.z, 32);
    acc.w += __shfl_xor(acc.w, 32);
    if (half == 0) {
        float sc = 1.f + epsp[0];
        float4 hn = ((const float4*)(h + (size_t)n * HDIM))[q];
        float4 o;
        o.x = fmaf(sc, hn.x, acc.x);
        o.y = fmaf(sc, hn.y, acc.y);
        o.z = fmaf(sc, hn.z, acc.z);
        o.w = fmaf(sc, hn.w, acc.w);
        ((float4*)(z + (size_t)n * HDIM))[q] = o;
    }
}

// ------------- MLP half: out = epilogue(Z @ W + bias) -------------
#define GROWS 128
__global__ __launch_bounds__(512, 1) void k_mlp(
    const float* __restrict__ A,
    const float* __restrict__ W, const float* __restrict__ bias,
    const float* __restrict__ gam, const float* __restrict__ bet,
    float* outp, int N, int mode) {
    __shared__ float zs[GROWS][129];
    __shared__ float wsm[128 * 128];
    int tid = threadIdx.x;
    int row0 = blockIdx.x * GROWS;

    #pragma unroll
    for (int i = 0; i < 8; ++i) {
        int c = tid + i * 512;
        ((float4*)wsm)[c] = ((const float4*)W)[c];
    }
    #pragma unroll
    for (int i = 0; i < 8; ++i) {
        int c = tid + i * 512;
        int r = c >> 5, k4 = c & 31;
        int gr = row0 + r;
        float4 z4 = make_float4(0.f, 0.f, 0.f, 0.f);
        if (gr < N) z4 = ((const float4*)(A + (size_t)gr * HDIM))[k4];
        zs[r][k4 * 4 + 0] = z4.x;
        zs[r][k4 * 4 + 1] = z4.y;
        zs[r][k4 * 4 + 2] = z4.z;
        zs[r][k4 * 4 + 3] = z4.w;
    }
    __syncthreads();

    int cg = tid & 15;
    int rg = tid >> 4;
    float acc[4][8];
    #pragma unroll
    for (int i = 0; i < 4; ++i)
        #pragma unroll
        for (int j = 0; j < 8; ++j) acc[i][j] = 0.f;

    #pragma unroll 4
    for (int k = 0; k < 128; ++k) {
        float aa[4];
        aa[0] = zs[rg][k];
        aa[1] = zs[rg + 32][k];
        aa[2] = zs[rg + 64][k];
        aa[3] = zs[rg + 96][k];
        float4 b0 = *(const float4*)&wsm[k * 128 + 4 * cg];
        float4 b1v = *(const float4*)&wsm[k * 128 + 64 + 4 * cg];
        float bb[8] = {b0.x, b0.y, b0.z, b0.w, b1v.x, b1v.y, b1v.z, b1v.w};
        #pragma unroll
        for (int i = 0; i < 4; ++i)
            #pragma unroll
            for (int j = 0; j < 8; ++j)
                acc[i][j] = fmaf(aa[i], bb[j], acc[i][j]);
    }

    float4 bl = ((const float4*)bias)[cg];
    float4 bh = ((const float4*)bias)[16 + cg];
    float bb_[8] = {bl.x, bl.y, bl.z, bl.w, bh.x, bh.y, bh.z, bh.w};
    float gg[8], tt[8];
    if (mode == 1) {
        float4 gl = ((const float4*)gam)[cg];
        float4 gh = ((const float4*)gam)[16 + cg];
        float4 tl = ((const float4*)bet)[cg];
        float4 th = ((const float4*)bet)[16 + cg];
        gg[0]=gl.x; gg[1]=gl.y; gg[2]=gl.z; gg[3]=gl.w;
        gg[4]=gh.x; gg[5]=gh.y; gg[6]=gh.z; gg[7]=gh.w;
        tt[0]=tl.x; tt[1]=tl.y; tt[2]=tl.z; tt[3]=tl.w;
        tt[4]=th.x; tt[5]=th.y; tt[6]=th.z; tt[7]=th.w;
    }
    #pragma unroll
    for (int i = 0; i < 4; ++i) {
        int gr = row0 + rg + 32 * i;
        if (gr < N) {
            float o[8];
            #pragma unroll
            for (int j = 0; j < 8; ++j) {
                float v = acc[i][j] + bb_[j];
                if (mode == 0) v = fmaxf(v, 0.f);
                else           v = fmaxf(fmaf(gg[j] * v, INVSTD, tt[j]), 0.f);
                o[j] = v;
            }
            *(float4*)(outp + (size_t)gr * HDIM + 4 * cg) = make_float4(o[0], o[1], o[2], o[3]);
            *(float4*)(outp + (size_t)gr * HDIM + 64 + 4 * cg) = make_float4(o[4], o[5], o[6], o[7]);
        }
    }
}

// ------------- pooling: segmented reduction over sorted batch -------------
#define PCHUNK 256
#define PWIN 4
__global__ __launch_bounds__(256) void k_pool2(const float* __restrict__ h,
                                               const int* __restrict__ batch,
                                               float* pooled, int N) {
    __shared__ float acc[PWIN][HDIM];
    int n0 = blockIdx.x * PCHUNK;
    if (n0 >= N) return;
    int n1 = min(n0 + PCHUNK, N);
    int g0 = batch[n0];
    int g1 = batch[n1 - 1];                 // sorted => window [g0, g1]
    for (int i = threadIdx.x; i < PWIN * HDIM; i += 256) ((float*)acc)[i] = 0.f;
    __syncthreads();

    int grp = threadIdx.x >> 5;             // 8 node-groups
    int q = threadIdx.x & 31;               // feature float4 index
    float4 racc = make_float4(0.f, 0.f, 0.f, 0.f);
    int gcur = g0;
    for (int n = n0 + grp; n < n1; n += 8) {
        int g = batch[n];
        if (g != gcur) {
            int w = gcur - g0;
            if (w < PWIN) {
                float* p = &acc[w][q * 4];
                atomicAdd(p + 0, racc.x); atomicAdd(p + 1, racc.y);
                atomicAdd(p + 2, racc.z); atomicAdd(p + 3, racc.w);
            } else {
                float* p = pooled + gcur * HDIM + q * 4;
                atomicAdd(p + 0, racc.x); atomicAdd(p + 1, racc.y);
                atomicAdd(p + 2, racc.z); atomicAdd(p + 3, racc.w);
            }
            racc = make_float4(0.f, 0.f, 0.f, 0.f);
            gcur = g;
        }
        float4 hv = ((const float4*)(h + (size_t)n * HDIM))[q];
        racc.x += hv.x; racc.y += hv.y; racc.z += hv.z; racc.w += hv.w;
    }
    {
        int w = gcur - g0;
        if (w < PWIN) {
            float* p = &acc[w][q * 4];
            atomicAdd(p + 0, racc.x); atomicAdd(p + 1, racc.y);
            atomicAdd(p + 2, racc.z); atomicAdd(p + 3, racc.w);
        } else {
            float* p = pooled + gcur * HDIM + q * 4;
            atomicAdd(p + 0, racc.x); atomicAdd(p + 1, racc.y);
            atomicAdd(p + 2, racc.z); atomicAdd(p + 3, racc.w);
        }
    }
    __syncthreads();

    int span = min(g1 - g0 + 1, PWIN);
    for (int i = threadIdx.x; i < span * HDIM; i += 256) {
        int w = i >> 7, f = i & 127;
        float v = acc[w][f];
        if (v != 0.f) atomicAdd(pooled + (g0 + w) * HDIM + f, v);
    }
}

// counts via binary search over sorted batch
__global__ void k_count(const int* __restrict__ batch, float* cnt, int N) {
    int g = threadIdx.x;
    if (g >= NGRAPH) return;
    int lo = 0, hi = N;
    while (lo < hi) { int m = (lo + hi) >> 1; if (batch[m] < g) lo = m + 1; else hi = m; }
    int lo2 = lo, hi2 = N;
    while (lo2 < hi2) { int m = (lo2 + hi2) >> 1; if (batch[m] < g + 1) lo2 = m + 1; else hi2 = m; }
    cnt[g] = (float)(lo2 - lo);
}

// ------------- classifier -------------
__global__ void k_classify(const float* __restrict__ pooled, const float* __restrict__ cnt,
                           const float* __restrict__ cw1, const float* __restrict__ cb1,
                           const float* __restrict__ cw2, const float* __restrict__ cb2,
                           float* __restrict__ out) {
    __shared__ float p[HDIM];
    int g = blockIdx.x, j = threadIdx.x;
    float c = fmaxf(cnt[g], 1.f);
    p[j]      = pooled[g * HDIM + j] / c;
    p[j + 64] = pooled[g * HDIM + j + 64] / c;
    __syncthreads();
    float acc = cb1[j];
    #pragma unroll 4
    for (int k = 0; k < HDIM; ++k) acc = fmaf(p[k], cw1[k * 64 + j], acc);
    acc = fmaxf(acc, 0.f);
    float v = acc * cw2[j];
    #pragma unroll
    for (int off = 32; off > 0; off >>= 1) v += __shfl_down(v, off, 64);
    if (j == 0) out[g] = 1.f / (1.f + expf(-(v + cb2[0])));
}

static inline size_t align_up(size_t v, size_t a) { return (v + a - 1) & ~(a - 1); }

extern "C" void kernel_launch(void* const* d_in, const int* in_sizes, int n_in,
                              void* d_out, int out_size, void* d_ws, size_t ws_size,
                              hipStream_t stream) {
    const float* x      = (const float*)d_in[0];
    const int*   ei     = (const int*)d_in[1];
    const float* eattr  = (const float*)d_in[2];
    const int*   batch  = (const int*)d_in[3];
    const float* enc_w  = (const float*)d_in[4];
    const float* enc_b  = (const float*)d_in[5];
    const float* eenc_w = (const float*)d_in[6];
    const float* eenc_b = (const float*)d_in[7];
    const float* eps    = (const float*)d_in[8];
    const float* w1     = (const float*)d_in[9];
    const float* b1     = (const float*)d_in[10];
    const float* w2     = (const float*)d_in[11];
    const float* b2     = (const float*)d_in[12];
    const float* gamma  = (const float*)d_in[13];
    const float* beta   = (const float*)d_in[14];
    const float* cw1    = (const float*)d_in[15];
    const float* cb1    = (const float*)d_in[16];
    const float* cw2    = (const float*)d_in[17];
    const float* cb2    = (const float*)d_in[18];

    int N = in_sizes[0];          // 100000
    int E = in_sizes[2];          // 1600000

    char* wsb = (char*)d_ws;
    size_t off = 0;
    size_t hbytes = (size_t)N * HDIM * sizeof(float);
    float* h      = (float*)(wsb + off); off = align_up(off + hbytes, 256);
    float* z      = (float*)(wsb + off); off = align_up(off + hbytes, 256);
    float* pooled = (float*)(wsb + off); off = align_up(off + NGRAPH * HDIM * 4, 256);
    float* cnt    = (float*)(wsb + off); off = align_up(off + NGRAPH * 4, 256);
    int*   deg    = (int*)(wsb + off);   off = align_up(off + (size_t)N * 4, 256);
    int*   rs     = (int*)(wsb + off);   off = align_up(off + (size_t)(N + 1) * 4, 256);
    int*   cur    = (int*)(wsb + off);   off = align_up(off + (size_t)N * 4, 256);
    int*   bsum   = (int*)(wsb + off);   off = align_up(off + 2048 * 4, 256);
    int*   es     = (int*)(wsb + off);   off = align_up(off + (size_t)E * 4, 256);
    float* ea     = (float*)(wsb + off); off = align_up(off + (size_t)E * 4, 256);

    int nb = (N + 255) / 256;

    // CSR build
    hipMemsetAsync(deg, 0, (size_t)N * 4, stream);
    k_hist<<<2048, 256, 0, stream>>>(ei, deg, E);
    k_scan1<<<nb, 256, 0, stream>>>(deg, rs, bsum, N);
    k_scan2<<<1, 512, 0, stream>>>(bsum, nb);
    k_scan3<<<(N + 256) / 256, 256, 0, stream>>>(rs, bsum, cur, N, E);
    k_scatter<<<2048, 256, 0, stream>>>(ei, eattr, cur, es, ea, E);

    hipMemsetAsync(pooled, 0, (NGRAPH * HDIM + NGRAPH) * sizeof(float), stream);
    k_encode<<<2048, 256, 0, stream>>>(x, enc_w, enc_b, h, N);

    int gblocks = (N + GROWS - 1) / GROWS;
    int ablocks = (N * 64 + 255) / 256;
    for (int l = 0; l < 2; ++l) {
        k_agg<<<ablocks, 256, 0, stream>>>(h, rs, es, ea, eenc_w, eenc_b, eps + l, z, N);
        k_mlp<<<gblocks, 512, 0, stream>>>(z, w1 + (size_t)l * HDIM * HDIM,
                                           b1 + l * HDIM, nullptr, nullptr, z, N, 0);
        k_mlp<<<gblocks, 512, 0, stream>>>(z, w2 + (size_t)l * HDIM * HDIM,
                                           b2 + l * HDIM, gamma + l * HDIM, beta + l * HDIM, h, N, 1);
    }

    k_pool2<<<(N + PCHUNK - 1) / PCHUNK, 256, 0, stream>>>(h, batch, pooled, N);
    k_count<<<1, 64, 0, stream>>>(batch, cnt, N);
    k_classify<<<NGRAPH, 64, 0, stream>>>(pooled, cnt, cw1, cb1, cw2, cb2, (float*)d_out);
}

// Round 4
// 723.009 us; speedup vs baseline: 9.0047x; 1.0500x over previous
//
#include <hip/hip_runtime.h>

#define HDIM 128
#define NGRAPH 64
#define INVSTD 0.99999500003749972f   // 1/sqrt(1+1e-5)

typedef unsigned short ushort_t;
typedef unsigned int uint_t;

__device__ __forceinline__ float bf2f(uint_t u) {        // u = 16-bit bf16 in low bits
    return __int_as_float((int)(u << 16));
}
__device__ __forceinline__ uint_t f2bf(float f) {        // RNE
    uint_t x = __float_as_uint(f);
    return (x + 0x7FFFu + ((x >> 16) & 1u)) >> 16;
}
__device__ __forceinline__ uint_t pack2(float a, float b) {
    return f2bf(a) | (f2bf(b) << 16);
}

// ---------------- encode: hb[n][k] = bf16(x[n]*ew[k] + eb[k]) ----------------
__global__ void k_encode(const float* __restrict__ x, const float* __restrict__ ew,
                         const float* __restrict__ eb, ushort_t* __restrict__ hb, int N) {
    int tid = blockIdx.x * blockDim.x + threadIdx.x;
    int stride = gridDim.x * blockDim.x;
    int q = tid & 15;                       // 16 lanes/node, 8 features each
    float4 wa = ((const float4*)ew)[2 * q];
    float4 wb = ((const float4*)ew)[2 * q + 1];
    float4 ba = ((const float4*)eb)[2 * q];
    float4 bb = ((const float4*)eb)[2 * q + 1];
    int total = N * 16;
    for (int t = tid; t < total; t += stride) {
        int n = t >> 4;
        float xv = x[n];
        uint4 o;
        o.x = pack2(fmaf(xv, wa.x, ba.x), fmaf(xv, wa.y, ba.y));
        o.y = pack2(fmaf(xv, wa.z, ba.z), fmaf(xv, wa.w, ba.w));
        o.z = pack2(fmaf(xv, wb.x, bb.x), fmaf(xv, wb.y, bb.y));
        o.w = pack2(fmaf(xv, wb.z, bb.z), fmaf(xv, wb.w, bb.w));
        ((uint4*)(hb + (size_t)n * HDIM))[q] = o;
    }
}

// ---------------- CSR build ----------------
__global__ void k_hist(const int* __restrict__ ei, int* deg, int E) {
    int tid = blockIdx.x * blockDim.x + threadIdx.x;
    int stride = gridDim.x * blockDim.x;
    for (int e = tid; e < E; e += stride) atomicAdd(&deg[ei[E + e]], 1);
}

__global__ void k_scan1(const int* __restrict__ deg, int* rs, int* bsum, int N) {
    __shared__ int sm[256];
    int gid = blockIdx.x * 256 + threadIdx.x;
    int v = (gid < N) ? deg[gid] : 0;
    sm[threadIdx.x] = v;
    __syncthreads();
    #pragma unroll
    for (int off = 1; off < 256; off <<= 1) {
        int t = (threadIdx.x >= off) ? sm[threadIdx.x - off] : 0;
        __syncthreads();
        sm[threadIdx.x] += t;
        __syncthreads();
    }
    if (gid < N) rs[gid] = sm[threadIdx.x] - v;
    if (threadIdx.x == 255) bsum[blockIdx.x] = sm[255];
}

__global__ void k_scan2(int* bsum, int nb) {
    __shared__ int sm[512];
    int t = threadIdx.x;
    int v = (t < nb) ? bsum[t] : 0;
    sm[t] = v;
    __syncthreads();
    #pragma unroll
    for (int off = 1; off < 512; off <<= 1) {
        int u = (t >= off) ? sm[t - off] : 0;
        __syncthreads();
        sm[t] += u;
        __syncthreads();
    }
    if (t < nb) bsum[t] = sm[t] - v;
}

__global__ void k_scan3(int* rs, const int* __restrict__ bsum, int* cur, int N, int E) {
    int gid = blockIdx.x * 256 + threadIdx.x;
    if (gid < N) {
        int v = rs[gid] + bsum[gid >> 8];
        rs[gid] = v;
        cur[gid] = v;
    }
    if (gid == N) rs[N] = E;
}

// packed scatter: one 8B store per edge
__global__ void k_scatter(const int* __restrict__ ei, const float* __restrict__ attr,
                          int* cur, int2* __restrict__ epack, int E) {
    int tid = blockIdx.x * blockDim.x + threadIdx.x;
    int stride = gridDim.x * blockDim.x;
    for (int e = tid; e < E; e += stride) {
        int s = ei[e], d = ei[E + e];
        int p = atomicAdd(&cur[d], 1);
        epack[p] = make_int2(s, __float_as_int(attr[e]));
    }
}

// ------- aggregation: one wave per dst node; bf16 gather -------
// z[n] = (1+eps)*h[n] + sum_e relu(h[src_e] + a_e*ew + eb)      (fp32 out)
__global__ __launch_bounds__(256) void k_agg(
    const ushort_t* __restrict__ hb, const int* __restrict__ rs,
    const int2* __restrict__ epack,
    const float* __restrict__ ew, const float* __restrict__ eb,
    const float* __restrict__ epsp, float* __restrict__ z, int N) {
    int wave = (blockIdx.x * 256 + threadIdx.x) >> 6;
    int lane = threadIdx.x & 63;
    int half = lane >> 5, q = lane & 31;        // q: features 4q..4q+3
    if (wave >= N) return;
    int n = wave;
    int beg = rs[n], end = rs[n + 1];
    float4 w4 = ((const float4*)ew)[q];
    float4 b4 = ((const float4*)eb)[q];
    float4 acc = make_float4(0.f, 0.f, 0.f, 0.f);
    for (int i = beg + half; i < end; i += 2) {
        int2 e = epack[i];
        int s = e.x;
        float a = __int_as_float(e.y);
        uint2 u = ((const uint2*)(hb + (size_t)s * HDIM))[q];
        acc.x += fmaxf(bf2f(u.x & 0xFFFFu) + fmaf(a, w4.x, b4.x), 0.f);
        acc.y += fmaxf(bf2f(u.x >> 16)     + fmaf(a, w4.y, b4.y), 0.f);
        acc.z += fmaxf(bf2f(u.y & 0xFFFFu) + fmaf(a, w4.z, b4.z), 0.f);
        acc.w += fmaxf(bf2f(u.y >> 16)     + fmaf(a, w4.w, b4.w), 0.f);
    }
    acc.x += __shfl_xor(acc.x, 32);
    acc.y += __shfl_xor(acc.y, 32);
    acc.z += __shfl_xor(acc.z, 32);
    acc.w += __shfl_xor(acc.w, 32);
    if (half == 0) {
        float sc = 1.f + epsp[0];
        uint2 u = ((const uint2*)(hb + (size_t)n * HDIM))[q];
        float4 o;
        o.x = fmaf(sc, bf2f(u.x & 0xFFFFu), acc.x);
        o.y = fmaf(sc, bf2f(u.x >> 16),     acc.y);
        o.z = fmaf(sc, bf2f(u.y & 0xFFFFu), acc.z);
        o.w = fmaf(sc, bf2f(u.y >> 16),     acc.w);
        ((float4*)(z + (size_t)n * HDIM))[q] = o;
    }
}

// ------------- MLP half: out = epilogue(Z @ W + bias) -------------
// mode 0: relu -> fp32 outp (aliases z);  mode 1: BN+relu -> bf16 hbout
#define GROWS 128
__global__ __launch_bounds__(512, 1) void k_mlp(
    const float* __restrict__ A,
    const float* __restrict__ W, const float* __restrict__ bias,
    const float* __restrict__ gam, const float* __restrict__ bet,
    float* outp, ushort_t* hbout, int N, int mode) {
    __shared__ float zs[GROWS][129];
    __shared__ float wsm[128 * 128];
    int tid = threadIdx.x;
    int row0 = blockIdx.x * GROWS;

    #pragma unroll
    for (int i = 0; i < 8; ++i) {
        int c = tid + i * 512;
        ((float4*)wsm)[c] = ((const float4*)W)[c];
    }
    #pragma unroll
    for (int i = 0; i < 8; ++i) {
        int c = tid + i * 512;
        int r = c >> 5, k4 = c & 31;
        int gr = row0 + r;
        float4 z4 = make_float4(0.f, 0.f, 0.f, 0.f);
        if (gr < N) z4 = ((const float4*)(A + (size_t)gr * HDIM))[k4];
        zs[r][k4 * 4 + 0] = z4.x;
        zs[r][k4 * 4 + 1] = z4.y;
        zs[r][k4 * 4 + 2] = z4.z;
        zs[r][k4 * 4 + 3] = z4.w;
    }
    __syncthreads();

    int cg = tid & 15;
    int rg = tid >> 4;
    float acc[4][8];
    #pragma unroll
    for (int i = 0; i < 4; ++i)
        #pragma unroll
        for (int j = 0; j < 8; ++j) acc[i][j] = 0.f;

    #pragma unroll 4
    for (int k = 0; k < 128; ++k) {
        float aa[4];
        aa[0] = zs[rg][k];
        aa[1] = zs[rg + 32][k];
        aa[2] = zs[rg + 64][k];
        aa[3] = zs[rg + 96][k];
        float4 b0 = *(const float4*)&wsm[k * 128 + 4 * cg];
        float4 b1v = *(const float4*)&wsm[k * 128 + 64 + 4 * cg];
        float bb[8] = {b0.x, b0.y, b0.z, b0.w, b1v.x, b1v.y, b1v.z, b1v.w};
        #pragma unroll
        for (int i = 0; i < 4; ++i)
            #pragma unroll
            for (int j = 0; j < 8; ++j)
                acc[i][j] = fmaf(aa[i], bb[j], acc[i][j]);
    }

    float4 bl = ((const float4*)bias)[cg];
    float4 bh = ((const float4*)bias)[16 + cg];
    float bb_[8] = {bl.x, bl.y, bl.z, bl.w, bh.x, bh.y, bh.z, bh.w};
    float gg[8], tt[8];
    if (mode == 1) {
        float4 gl = ((const float4*)gam)[cg];
        float4 gh = ((const float4*)gam)[16 + cg];
        float4 tl = ((const float4*)bet)[cg];
        float4 th = ((const float4*)bet)[16 + cg];
        gg[0]=gl.x; gg[1]=gl.y; gg[2]=gl.z; gg[3]=gl.w;
        gg[4]=gh.x; gg[5]=gh.y; gg[6]=gh.z; gg[7]=gh.w;
        tt[0]=tl.x; tt[1]=tl.y; tt[2]=tl.z; tt[3]=tl.w;
        tt[4]=th.x; tt[5]=th.y; tt[6]=th.z; tt[7]=th.w;
    }
    #pragma unroll
    for (int i = 0; i < 4; ++i) {
        int gr = row0 + rg + 32 * i;
        if (gr < N) {
            float o[8];
            #pragma unroll
            for (int j = 0; j < 8; ++j) {
                float v = acc[i][j] + bb_[j];
                if (mode == 0) v = fmaxf(v, 0.f);
                else           v = fmaxf(fmaf(gg[j] * v, INVSTD, tt[j]), 0.f);
                o[j] = v;
            }
            if (mode == 0) {
                *(float4*)(outp + (size_t)gr * HDIM + 4 * cg) = make_float4(o[0], o[1], o[2], o[3]);
                *(float4*)(outp + (size_t)gr * HDIM + 64 + 4 * cg) = make_float4(o[4], o[5], o[6], o[7]);
            } else {
                *(uint2*)(hbout + (size_t)gr * HDIM + 4 * cg) = make_uint2(pack2(o[0], o[1]), pack2(o[2], o[3]));
                *(uint2*)(hbout + (size_t)gr * HDIM + 64 + 4 * cg) = make_uint2(pack2(o[4], o[5]), pack2(o[6], o[7]));
            }
        }
    }
}

// ------------- pooling: segmented reduction over sorted batch (bf16 in) -------------
#define PCHUNK 256
#define PWIN 4
__global__ __launch_bounds__(256) void k_pool2(const ushort_t* __restrict__ hb,
                                               const int* __restrict__ batch,
                                               float* pooled, int N) {
    __shared__ float acc[PWIN][HDIM];
    int n0 = blockIdx.x * PCHUNK;
    if (n0 >= N) return;
    int n1 = min(n0 + PCHUNK, N);
    int g0 = batch[n0];
    int g1 = batch[n1 - 1];
    for (int i = threadIdx.x; i < PWIN * HDIM; i += 256) ((float*)acc)[i] = 0.f;
    __syncthreads();

    int grp = threadIdx.x >> 5;
    int q = threadIdx.x & 31;
    float4 racc = make_float4(0.f, 0.f, 0.f, 0.f);
    int gcur = g0;
    for (int n = n0 + grp; n < n1; n += 8) {
        int g = batch[n];
        if (g != gcur) {
            int w = gcur - g0;
            float* p = (w < PWIN) ? &acc[w][q * 4] : (pooled + gcur * HDIM + q * 4);
            atomicAdd(p + 0, racc.x); atomicAdd(p + 1, racc.y);
            atomicAdd(p + 2, racc.z); atomicAdd(p + 3, racc.w);
            racc = make_float4(0.f, 0.f, 0.f, 0.f);
            gcur = g;
        }
        uint2 u = ((const uint2*)(hb + (size_t)n * HDIM))[q];
        racc.x += bf2f(u.x & 0xFFFFu);
        racc.y += bf2f(u.x >> 16);
        racc.z += bf2f(u.y & 0xFFFFu);
        racc.w += bf2f(u.y >> 16);
    }
    {
        int w = gcur - g0;
        float* p = (w < PWIN) ? &acc[w][q * 4] : (pooled + gcur * HDIM + q * 4);
        atomicAdd(p + 0, racc.x); atomicAdd(p + 1, racc.y);
        atomicAdd(p + 2, racc.z); atomicAdd(p + 3, racc.w);
    }
    __syncthreads();

    int span = min(g1 - g0 + 1, PWIN);
    for (int i = threadIdx.x; i < span * HDIM; i += 256) {
        int w = i >> 7, f = i & 127;
        float v = acc[w][f];
        if (v != 0.f) atomicAdd(pooled + (g0 + w) * HDIM + f, v);
    }
}

__global__ void k_count(const int* __restrict__ batch, float* cnt, int N) {
    int g = threadIdx.x;
    if (g >= NGRAPH) return;
    int lo = 0, hi = N;
    while (lo < hi) { int m = (lo + hi) >> 1; if (batch[m] < g) lo = m + 1; else hi = m; }
    int lo2 = lo, hi2 = N;
    while (lo2 < hi2) { int m = (lo2 + hi2) >> 1; if (batch[m] < g + 1) lo2 = m + 1; else hi2 = m; }
    cnt[g] = (float)(lo2 - lo);
}

// ------------- classifier -------------
__global__ void k_classify(const float* __restrict__ pooled, const float* __restrict__ cnt,
                           const float* __restrict__ cw1, const float* __restrict__ cb1,
                           const float* __restrict__ cw2, const float* __restrict__ cb2,
                           float* __restrict__ out) {
    __shared__ float p[HDIM];
    int g = blockIdx.x, j = threadIdx.x;
    float c = fmaxf(cnt[g], 1.f);
    p[j]      = pooled[g * HDIM + j] / c;
    p[j + 64] = pooled[g * HDIM + j + 64] / c;
    __syncthreads();
    float acc = cb1[j];
    #pragma unroll 4
    for (int k = 0; k < HDIM; ++k) acc = fmaf(p[k], cw1[k * 64 + j], acc);
    acc = fmaxf(acc, 0.f);
    float v = acc * cw2[j];
    #pragma unroll
    for (int off = 32; off > 0; off >>= 1) v += __shfl_down(v, off, 64);
    if (j == 0) out[g] = 1.f / (1.f + expf(-(v + cb2[0])));
}

static inline size_t align_up(size_t v, size_t a) { return (v + a - 1) & ~(a - 1); }

extern "C" void kernel_launch(void* const* d_in, const int* in_sizes, int n_in,
                              void* d_out, int out_size, void* d_ws, size_t ws_size,
                              hipStream_t stream) {
    const float* x      = (const float*)d_in[0];
    const int*   ei     = (const int*)d_in[1];
    const float* eattr  = (const float*)d_in[2];
    const int*   batch  = (const int*)d_in[3];
    const float* enc_w  = (const float*)d_in[4];
    const float* enc_b  = (const float*)d_in[5];
    const float* eenc_w = (const float*)d_in[6];
    const float* eenc_b = (const float*)d_in[7];
    const float* eps    = (const float*)d_in[8];
    const float* w1     = (const float*)d_in[9];
    const float* b1     = (const float*)d_in[10];
    const float* w2     = (const float*)d_in[11];
    const float* b2     = (const float*)d_in[12];
    const float* gamma  = (const float*)d_in[13];
    const float* beta   = (const float*)d_in[14];
    const float* cw1    = (const float*)d_in[15];
    const float* cb1    = (const float*)d_in[16];
    const float* cw2    = (const float*)d_in[17];
    const float* cb2    = (const float*)d_in[18];

    int N = in_sizes[0];          // 100000
    int E = in_sizes[2];          // 1600000

    char* wsb = (char*)d_ws;
    size_t off = 0;
    ushort_t* hb  = (ushort_t*)(wsb + off); off = align_up(off + (size_t)N * HDIM * 2, 256);
    float* z      = (float*)(wsb + off);    off = align_up(off + (size_t)N * HDIM * 4, 256);
    float* pooled = (float*)(wsb + off);    off = align_up(off + NGRAPH * HDIM * 4, 256);
    float* cnt    = (float*)(wsb + off);    off = align_up(off + NGRAPH * 4, 256);
    int*   deg    = (int*)(wsb + off);      off = align_up(off + (size_t)N * 4, 256);
    int*   rs     = (int*)(wsb + off);      off = align_up(off + (size_t)(N + 1) * 4, 256);
    int*   cur    = (int*)(wsb + off);      off = align_up(off + (size_t)N * 4, 256);
    int*   bsum   = (int*)(wsb + off);      off = align_up(off + 2048 * 4, 256);
    int2*  epack  = (int2*)(wsb + off);     off = align_up(off + (size_t)E * 8, 256);

    int nb = (N + 255) / 256;

    // CSR build
    hipMemsetAsync(deg, 0, (size_t)N * 4, stream);
    k_hist<<<2048, 256, 0, stream>>>(ei, deg, E);
    k_scan1<<<nb, 256, 0, stream>>>(deg, rs, bsum, N);
    k_scan2<<<1, 512, 0, stream>>>(bsum, nb);
    k_scan3<<<(N + 256) / 256, 256, 0, stream>>>(rs, bsum, cur, N, E);
    k_scatter<<<2048, 256, 0, stream>>>(ei, eattr, cur, epack, E);

    hipMemsetAsync(pooled, 0, (NGRAPH * HDIM + NGRAPH) * sizeof(float), stream);
    k_encode<<<2048, 256, 0, stream>>>(x, enc_w, enc_b, hb, N);

    int gblocks = (N + GROWS - 1) / GROWS;
    int ablocks = (N * 64 + 255) / 256;
    for (int l = 0; l < 2; ++l) {
        k_agg<<<ablocks, 256, 0, stream>>>(hb, rs, epack, eenc_w, eenc_b, eps + l, z, N);
        k_mlp<<<gblocks, 512, 0, stream>>>(z, w1 + (size_t)l * HDIM * HDIM,
                                           b1 + l * HDIM, nullptr, nullptr, z, nullptr, N, 0);
        k_mlp<<<gblocks, 512, 0, stream>>>(z, w2 + (size_t)l * HDIM * HDIM,
                                           b2 + l * HDIM, gamma + l * HDIM, beta + l * HDIM,
                                           nullptr, hb, N, 1);
    }

    k_pool2<<<(N + PCHUNK - 1) / PCHUNK, 256, 0, stream>>>(hb, batch, pooled, N);
    k_count<<<1, 64, 0, stream>>>(batch, cnt, N);
    k_classify<<<NGRAPH, 64, 0, stream>>>(pooled, cnt, cw1, cb1, cw2, cb2, (float*)d_out);
}

// Round 5
// 433.385 us; speedup vs baseline: 15.0225x; 1.6683x over previous
//
#include <hip/hip_runtime.h>

#define HDIM 128
#define NGRAPH 64
#define INVSTD 0.99999500003749972f   // 1/sqrt(1+1e-5)

typedef unsigned short ushort_t;
typedef unsigned int uint_t;
typedef __attribute__((ext_vector_type(8))) short bf16x8;   // 8 bf16 = 4 VGPR
typedef __attribute__((ext_vector_type(4))) float f32x4;

__device__ __forceinline__ float bf2f(uint_t u) {
    return __int_as_float((int)(u << 16));
}
__device__ __forceinline__ uint_t f2bf(float f) {            // RNE
    uint_t x = __float_as_uint(f);
    return (x + 0x7FFFu + ((x >> 16) & 1u)) >> 16;
}
__device__ __forceinline__ uint_t pack2(float a, float b) {
    return f2bf(a) | (f2bf(b) << 16);
}

// ---------------- encode: hb[n][k] = bf16(x[n]*ew[k] + eb[k]) ----------------
__global__ void k_encode(const float* __restrict__ x, const float* __restrict__ ew,
                         const float* __restrict__ eb, ushort_t* __restrict__ hb, int N) {
    int tid = blockIdx.x * blockDim.x + threadIdx.x;
    int stride = gridDim.x * blockDim.x;
    int q = tid & 15;
    float4 wa = ((const float4*)ew)[2 * q];
    float4 wb = ((const float4*)ew)[2 * q + 1];
    float4 ba = ((const float4*)eb)[2 * q];
    float4 bb = ((const float4*)eb)[2 * q + 1];
    int total = N * 16;
    for (int t = tid; t < total; t += stride) {
        int n = t >> 4;
        float xv = x[n];
        uint4 o;
        o.x = pack2(fmaf(xv, wa.x, ba.x), fmaf(xv, wa.y, ba.y));
        o.y = pack2(fmaf(xv, wa.z, ba.z), fmaf(xv, wa.w, ba.w));
        o.z = pack2(fmaf(xv, wb.x, bb.x), fmaf(xv, wb.y, bb.y));
        o.w = pack2(fmaf(xv, wb.z, bb.z), fmaf(xv, wb.w, bb.w));
        ((uint4*)(hb + (size_t)n * HDIM))[q] = o;
    }
}

// ---------------- CSR build ----------------
// hist + rank in one pass: rank[e] = order of e among edges with same dst
__global__ void k_hist(const int* __restrict__ ei, int* deg, int* __restrict__ rank_, int E) {
    int e = blockIdx.x * 256 + threadIdx.x;
    if (e < E) {
        int d = ei[E + e];
        rank_[e] = atomicAdd(&deg[d], 1);
    }
}

__global__ void k_scan1(const int* __restrict__ deg, int* rs, int* bsum, int N) {
    __shared__ int sm[256];
    int gid = blockIdx.x * 256 + threadIdx.x;
    int v = (gid < N) ? deg[gid] : 0;
    sm[threadIdx.x] = v;
    __syncthreads();
    #pragma unroll
    for (int off = 1; off < 256; off <<= 1) {
        int t = (threadIdx.x >= off) ? sm[threadIdx.x - off] : 0;
        __syncthreads();
        sm[threadIdx.x] += t;
        __syncthreads();
    }
    if (gid < N) rs[gid] = sm[threadIdx.x] - v;
    if (threadIdx.x == 255) bsum[blockIdx.x] = sm[255];
}

__global__ void k_scan2(int* bsum, int nb) {
    __shared__ int sm[512];
    int t = threadIdx.x;
    int v = (t < nb) ? bsum[t] : 0;
    sm[t] = v;
    __syncthreads();
    #pragma unroll
    for (int off = 1; off < 512; off <<= 1) {
        int u = (t >= off) ? sm[t - off] : 0;
        __syncthreads();
        sm[t] += u;
        __syncthreads();
    }
    if (t < nb) bsum[t] = sm[t] - v;
}

__global__ void k_scan3(int* rs, const int* __restrict__ bsum, int N, int E) {
    int gid = blockIdx.x * 256 + threadIdx.x;
    if (gid < N) rs[gid] += bsum[gid >> 8];
    if (gid == N) rs[N] = E;
}

// scatter with precomputed rank: no atomic, no dependency chain
__global__ void k_scatter(const int* __restrict__ ei, const float* __restrict__ attr,
                          const int* __restrict__ rs, const int* __restrict__ rank_,
                          int2* __restrict__ epack, int E) {
    int e = blockIdx.x * 256 + threadIdx.x;
    if (e < E) {
        int s = ei[e], d = ei[E + e];
        int p = rs[d] + rank_[e];
        epack[p] = make_int2(s, __float_as_int(attr[e]));
    }
}

// ------- aggregation: one wave per dst node; bf16 gather, bf16 z out -------
// zb[n] = bf16( (1+eps)*h[n] + sum_e relu(h[src_e] + a_e*ew + eb) )
__global__ __launch_bounds__(256) void k_agg(
    const ushort_t* __restrict__ hb, const int* __restrict__ rs,
    const int2* __restrict__ epack,
    const float* __restrict__ ew, const float* __restrict__ eb,
    const float* __restrict__ epsp, ushort_t* __restrict__ zb, int N) {
    int wave = (blockIdx.x * 256 + threadIdx.x) >> 6;
    int lane = threadIdx.x & 63;
    int half = lane >> 5, q = lane & 31;
    if (wave >= N) return;
    int n = wave;
    int beg = rs[n], end = rs[n + 1];
    float4 w4 = ((const float4*)ew)[q];
    float4 b4 = ((const float4*)eb)[q];
    float4 acc = make_float4(0.f, 0.f, 0.f, 0.f);
    for (int i = beg + half; i < end; i += 2) {
        int2 e = epack[i];
        int s = e.x;
        float a = __int_as_float(e.y);
        uint2 u = ((const uint2*)(hb + (size_t)s * HDIM))[q];
        acc.x += fmaxf(bf2f(u.x & 0xFFFFu) + fmaf(a, w4.x, b4.x), 0.f);
        acc.y += fmaxf(bf2f(u.x >> 16)     + fmaf(a, w4.y, b4.y), 0.f);
        acc.z += fmaxf(bf2f(u.y & 0xFFFFu) + fmaf(a, w4.z, b4.z), 0.f);
        acc.w += fmaxf(bf2f(u.y >> 16)     + fmaf(a, w4.w, b4.w), 0.f);
    }
    acc.x += __shfl_xor(acc.x, 32);
    acc.y += __shfl_xor(acc.y, 32);
    acc.z += __shfl_xor(acc.z, 32);
    acc.w += __shfl_xor(acc.w, 32);
    if (half == 0) {
        float sc = 1.f + epsp[0];
        uint2 u = ((const uint2*)(hb + (size_t)n * HDIM))[q];
        uint2 ob;
        ob.x = pack2(fmaf(sc, bf2f(u.x & 0xFFFFu), acc.x),
                     fmaf(sc, bf2f(u.x >> 16),     acc.y));
        ob.y = pack2(fmaf(sc, bf2f(u.y & 0xFFFFu), acc.z),
                     fmaf(sc, bf2f(u.y >> 16),     acc.w));
        ((uint2*)(zb + (size_t)n * HDIM))[q] = ob;
    }
}

// ------------- MFMA GEMM: out = epilogue(A @ W + bias), all [*,128] -------------
// MODE 0: relu;  MODE 1: relu(gamma*v*INVSTD + beta).  A,out bf16; W fp32 input.
// Block: 256 thr (4 waves), 128 rows (2 iters x 4 waves x 16 rows).
#define WTPAD 136
template<int MODE>
__global__ __launch_bounds__(256) void k_gemm(
    const ushort_t* __restrict__ A, const float* __restrict__ W,
    const float* __restrict__ bias, const float* __restrict__ gam,
    const float* __restrict__ bet, ushort_t* __restrict__ out, int N) {
    __shared__ ushort_t wt[128 * WTPAD];        // wt[n][k] = bf16(W[k][n])
    int tid = threadIdx.x;
    #pragma unroll
    for (int i = 0; i < 64; ++i) {
        int idx = i * 256 + tid;                // coalesced read of W
        int k = idx >> 7, n = idx & 127;
        wt[n * WTPAD + k] = (ushort_t)f2bf(W[idx]);
    }
    __syncthreads();

    int wid = tid >> 6, lane = tid & 63;
    int ra = lane & 15, qa = lane >> 4;

    // cache all 32 B-fragments in registers
    bf16x8 bfr[4][8];
    #pragma unroll
    for (int ks = 0; ks < 4; ++ks)
        #pragma unroll
        for (int nf = 0; nf < 8; ++nf)
            bfr[ks][nf] = *(const bf16x8*)&wt[(nf * 16 + ra) * WTPAD + ks * 32 + qa * 8];

    float bi[8], gg[8], be[8];
    #pragma unroll
    for (int nf = 0; nf < 8; ++nf) {
        int col = nf * 16 + ra;
        bi[nf] = bias[col];
        if (MODE == 1) { gg[nf] = gam[col]; be[nf] = bet[col]; }
    }

    bf16x8 azero;
    #pragma unroll
    for (int j = 0; j < 8; ++j) azero[j] = 0;

    #pragma unroll
    for (int it = 0; it < 2; ++it) {
        int m0 = blockIdx.x * 128 + it * 64 + wid * 16;
        int mr = m0 + ra;
        bf16x8 afr[4];
        #pragma unroll
        for (int ks = 0; ks < 4; ++ks)
            afr[ks] = (mr < N) ? *(const bf16x8*)&A[(size_t)mr * HDIM + ks * 32 + qa * 8]
                               : azero;
        f32x4 acc[8];
        #pragma unroll
        for (int nf = 0; nf < 8; ++nf)
            #pragma unroll
            for (int j = 0; j < 4; ++j) acc[nf][j] = 0.f;
        #pragma unroll
        for (int ks = 0; ks < 4; ++ks)
            #pragma unroll
            for (int nf = 0; nf < 8; ++nf)
                acc[nf] = __builtin_amdgcn_mfma_f32_16x16x32_bf16(afr[ks], bfr[ks][nf], acc[nf], 0, 0, 0);
        // epilogue: D row = m0 + qa*4 + r, col = nf*16 + ra
        #pragma unroll
        for (int nf = 0; nf < 8; ++nf) {
            #pragma unroll
            for (int r = 0; r < 4; ++r) {
                int row = m0 + qa * 4 + r;
                if (row < N) {
                    float v = acc[nf][r] + bi[nf];
                    if (MODE == 0) v = fmaxf(v, 0.f);
                    else           v = fmaxf(fmaf(gg[nf] * v, INVSTD, be[nf]), 0.f);
                    out[(size_t)row * HDIM + nf * 16 + ra] = (ushort_t)f2bf(v);
                }
            }
        }
    }
}

// ------------- pooling: segmented reduction over sorted batch (bf16 in) -------------
#define PCHUNK 256
#define PWIN 4
__global__ __launch_bounds__(256) void k_pool2(const ushort_t* __restrict__ hb,
                                               const int* __restrict__ batch,
                                               float* pooled, int N) {
    __shared__ float acc[PWIN][HDIM];
    int n0 = blockIdx.x * PCHUNK;
    if (n0 >= N) return;
    int n1 = min(n0 + PCHUNK, N);
    int g0 = batch[n0];
    int g1 = batch[n1 - 1];
    for (int i = threadIdx.x; i < PWIN * HDIM; i += 256) ((float*)acc)[i] = 0.f;
    __syncthreads();

    int grp = threadIdx.x >> 5;
    int q = threadIdx.x & 31;
    float4 racc = make_float4(0.f, 0.f, 0.f, 0.f);
    int gcur = g0;
    for (int n = n0 + grp; n < n1; n += 8) {
        int g = batch[n];
        if (g != gcur) {
            int w = gcur - g0;
            float* p = (w < PWIN) ? &acc[w][q * 4] : (pooled + gcur * HDIM + q * 4);
            atomicAdd(p + 0, racc.x); atomicAdd(p + 1, racc.y);
            atomicAdd(p + 2, racc.z); atomicAdd(p + 3, racc.w);
            racc = make_float4(0.f, 0.f, 0.f, 0.f);
            gcur = g;
        }
        uint2 u = ((const uint2*)(hb + (size_t)n * HDIM))[q];
        racc.x += bf2f(u.x & 0xFFFFu);
        racc.y += bf2f(u.x >> 16);
        racc.z += bf2f(u.y & 0xFFFFu);
        racc.w += bf2f(u.y >> 16);
    }
    {
        int w = gcur - g0;
        float* p = (w < PWIN) ? &acc[w][q * 4] : (pooled + gcur * HDIM + q * 4);
        atomicAdd(p + 0, racc.x); atomicAdd(p + 1, racc.y);
        atomicAdd(p + 2, racc.z); atomicAdd(p + 3, racc.w);
    }
    __syncthreads();

    int span = min(g1 - g0 + 1, PWIN);
    for (int i = threadIdx.x; i < span * HDIM; i += 256) {
        int w = i >> 7, f = i & 127;
        float v = acc[w][f];
        if (v != 0.f) atomicAdd(pooled + (g0 + w) * HDIM + f, v);
    }
}

__global__ void k_count(const int* __restrict__ batch, float* cnt, int N) {
    int g = threadIdx.x;
    if (g >= NGRAPH) return;
    int lo = 0, hi = N;
    while (lo < hi) { int m = (lo + hi) >> 1; if (batch[m] < g) lo = m + 1; else hi = m; }
    int lo2 = lo, hi2 = N;
    while (lo2 < hi2) { int m = (lo2 + hi2) >> 1; if (batch[m] < g + 1) lo2 = m + 1; else hi2 = m; }
    cnt[g] = (float)(lo2 - lo);
}

// ------------- classifier -------------
__global__ void k_classify(const float* __restrict__ pooled, const float* __restrict__ cnt,
                           const float* __restrict__ cw1, const float* __restrict__ cb1,
                           const float* __restrict__ cw2, const float* __restrict__ cb2,
                           float* __restrict__ out) {
    __shared__ float p[HDIM];
    int g = blockIdx.x, j = threadIdx.x;
    float c = fmaxf(cnt[g], 1.f);
    p[j]      = pooled[g * HDIM + j] / c;
    p[j + 64] = pooled[g * HDIM + j + 64] / c;
    __syncthreads();
    float acc = cb1[j];
    #pragma unroll 4
    for (int k = 0; k < HDIM; ++k) acc = fmaf(p[k], cw1[k * 64 + j], acc);
    acc = fmaxf(acc, 0.f);
    float v = acc * cw2[j];
    #pragma unroll
    for (int off = 32; off > 0; off >>= 1) v += __shfl_down(v, off, 64);
    if (j == 0) out[g] = 1.f / (1.f + expf(-(v + cb2[0])));
}

static inline size_t align_up(size_t v, size_t a) { return (v + a - 1) & ~(a - 1); }

extern "C" void kernel_launch(void* const* d_in, const int* in_sizes, int n_in,
                              void* d_out, int out_size, void* d_ws, size_t ws_size,
                              hipStream_t stream) {
    const float* x      = (const float*)d_in[0];
    const int*   ei     = (const int*)d_in[1];
    const float* eattr  = (const float*)d_in[2];
    const int*   batch  = (const int*)d_in[3];
    const float* enc_w  = (const float*)d_in[4];
    const float* enc_b  = (const float*)d_in[5];
    const float* eenc_w = (const float*)d_in[6];
    const float* eenc_b = (const float*)d_in[7];
    const float* eps    = (const float*)d_in[8];
    const float* w1     = (const float*)d_in[9];
    const float* b1     = (const float*)d_in[10];
    const float* w2     = (const float*)d_in[11];
    const float* b2     = (const float*)d_in[12];
    const float* gamma  = (const float*)d_in[13];
    const float* beta   = (const float*)d_in[14];
    const float* cw1    = (const float*)d_in[15];
    const float* cb1    = (const float*)d_in[16];
    const float* cw2    = (const float*)d_in[17];
    const float* cb2    = (const float*)d_in[18];

    int N = in_sizes[0];          // 100000
    int E = in_sizes[2];          // 1600000

    char* wsb = (char*)d_ws;
    size_t off = 0;
    ushort_t* hb  = (ushort_t*)(wsb + off); off = align_up(off + (size_t)N * HDIM * 2, 256);
    ushort_t* zb  = (ushort_t*)(wsb + off); off = align_up(off + (size_t)N * HDIM * 2, 256);
    float* pooled = (float*)(wsb + off);    off = align_up(off + NGRAPH * HDIM * 4, 256);
    float* cnt    = (float*)(wsb + off);    off = align_up(off + NGRAPH * 4, 256);
    int*   deg    = (int*)(wsb + off);      off = align_up(off + (size_t)N * 4, 256);
    int*   rs     = (int*)(wsb + off);      off = align_up(off + (size_t)(N + 1) * 4, 256);
    int*   rank_  = (int*)(wsb + off);      off = align_up(off + (size_t)E * 4, 256);
    int*   bsum   = (int*)(wsb + off);      off = align_up(off + 2048 * 4, 256);
    int2*  epack  = (int2*)(wsb + off);     off = align_up(off + (size_t)E * 8, 256);

    int nb = (N + 255) / 256;
    int eb_blocks = (E + 255) / 256;

    // CSR build
    hipMemsetAsync(deg, 0, (size_t)N * 4, stream);
    k_hist<<<eb_blocks, 256, 0, stream>>>(ei, deg, rank_, E);
    k_scan1<<<nb, 256, 0, stream>>>(deg, rs, bsum, N);
    k_scan2<<<1, 512, 0, stream>>>(bsum, nb);
    k_scan3<<<(N + 256) / 256, 256, 0, stream>>>(rs, bsum, N, E);
    k_scatter<<<eb_blocks, 256, 0, stream>>>(ei, eattr, rs, rank_, epack, E);

    hipMemsetAsync(pooled, 0, (NGRAPH * HDIM + NGRAPH) * sizeof(float), stream);
    k_encode<<<2048, 256, 0, stream>>>(x, enc_w, enc_b, hb, N);

    int gblocks = (N + 127) / 128;
    int ablocks = (N * 64 + 255) / 256;
    for (int l = 0; l < 2; ++l) {
        k_agg<<<ablocks, 256, 0, stream>>>(hb, rs, epack, eenc_w, eenc_b, eps + l, zb, N);
        // GEMM1 (in-place: each block reads its own rows before writing them)
        k_gemm<0><<<gblocks, 256, 0, stream>>>(zb, w1 + (size_t)l * HDIM * HDIM,
                                               b1 + l * HDIM, nullptr, nullptr, zb, N);
        // GEMM2 -> hb (bf16), BN+relu fused
        k_gemm<1><<<gblocks, 256, 0, stream>>>(zb, w2 + (size_t)l * HDIM * HDIM,
                                               b2 + l * HDIM, gamma + l * HDIM, beta + l * HDIM,
                                               hb, N);
    }

    k_pool2<<<(N + PCHUNK - 1) / PCHUNK, 256, 0, stream>>>(hb, batch, pooled, N);
    k_count<<<1, 64, 0, stream>>>(batch, cnt, N);
    k_classify<<<NGRAPH, 64, 0, stream>>>(pooled, cnt, cw1, cb1, cw2, cb2, (float*)d_out);
}

// Round 6
// 380.567 us; speedup vs baseline: 17.1074x; 1.1388x over previous
//
#include <hip/hip_runtime.h>

#define HDIM 128
#define NGRAPH 64
#define INVSTD 0.99999500003749972f   // 1/sqrt(1+1e-5)

typedef unsigned short ushort_t;
typedef unsigned int uint_t;
typedef __attribute__((ext_vector_type(8))) short bf16x8;   // 8 bf16 = 4 VGPR
typedef __attribute__((ext_vector_type(4))) float f32x4;

__device__ __forceinline__ float bf2f(uint_t u) {
    return __int_as_float((int)(u << 16));
}
__device__ __forceinline__ uint_t f2bf(float f) {            // RNE
    uint_t x = __float_as_uint(f);
    return (x + 0x7FFFu + ((x >> 16) & 1u)) >> 16;
}
__device__ __forceinline__ uint_t pack2(float a, float b) {
    return f2bf(a) | (f2bf(b) << 16);
}

// ---------------- encode: hb[n][k] = bf16(x[n]*ew[k] + eb[k]) ----------------
__global__ void k_encode(const float* __restrict__ x, const float* __restrict__ ew,
                         const float* __restrict__ eb, ushort_t* __restrict__ hb, int N) {
    int tid = blockIdx.x * blockDim.x + threadIdx.x;
    int stride = gridDim.x * blockDim.x;
    int q = tid & 15;
    float4 wa = ((const float4*)ew)[2 * q];
    float4 wb = ((const float4*)ew)[2 * q + 1];
    float4 ba = ((const float4*)eb)[2 * q];
    float4 bb = ((const float4*)eb)[2 * q + 1];
    int total = N * 16;
    for (int t = tid; t < total; t += stride) {
        int n = t >> 4;
        float xv = x[n];
        uint4 o;
        o.x = pack2(fmaf(xv, wa.x, ba.x), fmaf(xv, wa.y, ba.y));
        o.y = pack2(fmaf(xv, wa.z, ba.z), fmaf(xv, wa.w, ba.w));
        o.z = pack2(fmaf(xv, wb.x, bb.x), fmaf(xv, wb.y, bb.y));
        o.w = pack2(fmaf(xv, wb.z, bb.z), fmaf(xv, wb.w, bb.w));
        ((uint4*)(hb + (size_t)n * HDIM))[q] = o;
    }
}

// ---------------- CSR build ----------------
__global__ void k_hist(const int* __restrict__ ei, int* deg, int* __restrict__ rank_, int E) {
    int e = blockIdx.x * 256 + threadIdx.x;
    if (e < E) {
        int d = ei[E + e];
        rank_[e] = atomicAdd(&deg[d], 1);
    }
}

__global__ void k_scan1(const int* __restrict__ deg, int* rs, int* bsum, int N) {
    __shared__ int sm[256];
    int gid = blockIdx.x * 256 + threadIdx.x;
    int v = (gid < N) ? deg[gid] : 0;
    sm[threadIdx.x] = v;
    __syncthreads();
    #pragma unroll
    for (int off = 1; off < 256; off <<= 1) {
        int t = (threadIdx.x >= off) ? sm[threadIdx.x - off] : 0;
        __syncthreads();
        sm[threadIdx.x] += t;
        __syncthreads();
    }
    if (gid < N) rs[gid] = sm[threadIdx.x] - v;
    if (threadIdx.x == 255) bsum[blockIdx.x] = sm[255];
}

__global__ void k_scan2(int* bsum, int nb) {
    __shared__ int sm[512];
    int t = threadIdx.x;
    int v = (t < nb) ? bsum[t] : 0;
    sm[t] = v;
    __syncthreads();
    #pragma unroll
    for (int off = 1; off < 512; off <<= 1) {
        int u = (t >= off) ? sm[t - off] : 0;
        __syncthreads();
        sm[t] += u;
        __syncthreads();
    }
    if (t < nb) bsum[t] = sm[t] - v;
}

__global__ void k_scan3(int* rs, const int* __restrict__ bsum, int N, int E) {
    int gid = blockIdx.x * 256 + threadIdx.x;
    if (gid < N) rs[gid] += bsum[gid >> 8];
    if (gid == N) rs[N] = E;
}

__global__ void k_scatter(const int* __restrict__ ei, const float* __restrict__ attr,
                          const int* __restrict__ rs, const int* __restrict__ rank_,
                          int2* __restrict__ epack, int E) {
    int e = blockIdx.x * 256 + threadIdx.x;
    if (e < E) {
        int s = ei[e], d = ei[E + e];
        int p = rs[d] + rank_[e];
        epack[p] = make_int2(s, __float_as_int(attr[e]));
    }
}

// ------- aggregation: 16 lanes per edge, uint4 gathers, 2-deep unroll -------
// zb[n] = bf16( (1+eps)*h[n] + sum_e relu(h[src_e] + a_e*ew + eb) )
__device__ __forceinline__ void acc_edge(float acc[8], const uint4& u, float at,
        const float4& wa, const float4& wb, const float4& ba, const float4& bb) {
    acc[0] += fmaxf(bf2f(u.x & 0xFFFFu) + fmaf(at, wa.x, ba.x), 0.f);
    acc[1] += fmaxf(bf2f(u.x >> 16)     + fmaf(at, wa.y, ba.y), 0.f);
    acc[2] += fmaxf(bf2f(u.y & 0xFFFFu) + fmaf(at, wa.z, ba.z), 0.f);
    acc[3] += fmaxf(bf2f(u.y >> 16)     + fmaf(at, wa.w, ba.w), 0.f);
    acc[4] += fmaxf(bf2f(u.z & 0xFFFFu) + fmaf(at, wb.x, bb.x), 0.f);
    acc[5] += fmaxf(bf2f(u.z >> 16)     + fmaf(at, wb.y, bb.y), 0.f);
    acc[6] += fmaxf(bf2f(u.w & 0xFFFFu) + fmaf(at, wb.z, bb.z), 0.f);
    acc[7] += fmaxf(bf2f(u.w >> 16)     + fmaf(at, wb.w, bb.w), 0.f);
}

__global__ __launch_bounds__(256) void k_agg(
    const ushort_t* __restrict__ hb, const int* __restrict__ rs,
    const int2* __restrict__ epack,
    const float* __restrict__ ew, const float* __restrict__ eb,
    const float* __restrict__ epsp, ushort_t* __restrict__ zb, int N) {
    int wave = (blockIdx.x * 256 + threadIdx.x) >> 6;
    if (wave >= N) return;
    int lane = threadIdx.x & 63;
    int p = lane >> 4;          // quarter-wave 0..3: handles edges j ≡ p (mod 4)
    int q = lane & 15;          // feature group: features 8q..8q+7
    int n = wave;
    int beg = rs[n];
    int cntE = rs[n + 1] - beg;
    float4 wa = ((const float4*)ew)[2 * q], wb = ((const float4*)ew)[2 * q + 1];
    float4 ba = ((const float4*)eb)[2 * q], bb = ((const float4*)eb)[2 * q + 1];

    float acc[8] = {0.f, 0.f, 0.f, 0.f, 0.f, 0.f, 0.f, 0.f};
    float acc2[8] = {0.f, 0.f, 0.f, 0.f, 0.f, 0.f, 0.f, 0.f};
    int j = p;
    // two independent gather→accumulate chains per quarter-wave
    for (; j + 4 < cntE; j += 8) {
        int2 e1 = epack[beg + j];
        int2 e2 = epack[beg + j + 4];
        uint4 u1 = *(const uint4*)(hb + (size_t)e1.x * HDIM + q * 8);
        uint4 u2 = *(const uint4*)(hb + (size_t)e2.x * HDIM + q * 8);
        acc_edge(acc,  u1, __int_as_float(e1.y), wa, wb, ba, bb);
        acc_edge(acc2, u2, __int_as_float(e2.y), wa, wb, ba, bb);
    }
    if (j < cntE) {
        int2 e1 = epack[beg + j];
        uint4 u1 = *(const uint4*)(hb + (size_t)e1.x * HDIM + q * 8);
        acc_edge(acc, u1, __int_as_float(e1.y), wa, wb, ba, bb);
    }
    #pragma unroll
    for (int k = 0; k < 8; ++k) {
        float v = acc[k] + acc2[k];
        v += __shfl_xor(v, 16);
        v += __shfl_xor(v, 32);
        acc[k] = v;
    }
    if (p == 0) {
        float sc = 1.f + epsp[0];
        uint4 u = *(const uint4*)(hb + (size_t)n * HDIM + q * 8);
        uint4 ob;
        ob.x = pack2(fmaf(sc, bf2f(u.x & 0xFFFFu), acc[0]),
                     fmaf(sc, bf2f(u.x >> 16),     acc[1]));
        ob.y = pack2(fmaf(sc, bf2f(u.y & 0xFFFFu), acc[2]),
                     fmaf(sc, bf2f(u.y >> 16),     acc[3]));
        ob.z = pack2(fmaf(sc, bf2f(u.z & 0xFFFFu), acc[4]),
                     fmaf(sc, bf2f(u.z >> 16),     acc[5]));
        ob.w = pack2(fmaf(sc, bf2f(u.w & 0xFFFFu), acc[6]),
                     fmaf(sc, bf2f(u.w >> 16),     acc[7]));
        *(uint4*)(zb + (size_t)n * HDIM + q * 8) = ob;
    }
}

// ------------- MFMA GEMM: out = epilogue(A @ W + bias), all [*,128] -------------
#define WTPAD 136
template<int MODE>
__global__ __launch_bounds__(256) void k_gemm(
    const ushort_t* __restrict__ A, const float* __restrict__ W,
    const float* __restrict__ bias, const float* __restrict__ gam,
    const float* __restrict__ bet, ushort_t* __restrict__ out, int N) {
    __shared__ ushort_t wt[128 * WTPAD];        // wt[n][k] = bf16(W[k][n])
    int tid = threadIdx.x;
    #pragma unroll
    for (int i = 0; i < 64; ++i) {
        int idx = i * 256 + tid;
        int k = idx >> 7, n = idx & 127;
        wt[n * WTPAD + k] = (ushort_t)f2bf(W[idx]);
    }
    __syncthreads();

    int wid = tid >> 6, lane = tid & 63;
    int ra = lane & 15, qa = lane >> 4;

    bf16x8 bfr[4][8];
    #pragma unroll
    for (int ks = 0; ks < 4; ++ks)
        #pragma unroll
        for (int nf = 0; nf < 8; ++nf)
            bfr[ks][nf] = *(const bf16x8*)&wt[(nf * 16 + ra) * WTPAD + ks * 32 + qa * 8];

    float bi[8], gg[8], be[8];
    #pragma unroll
    for (int nf = 0; nf < 8; ++nf) {
        int col = nf * 16 + ra;
        bi[nf] = bias[col];
        if (MODE == 1) { gg[nf] = gam[col]; be[nf] = bet[col]; }
    }

    bf16x8 azero;
    #pragma unroll
    for (int j = 0; j < 8; ++j) azero[j] = 0;

    #pragma unroll
    for (int it = 0; it < 2; ++it) {
        int m0 = blockIdx.x * 128 + it * 64 + wid * 16;
        int mr = m0 + ra;
        bf16x8 afr[4];
        #pragma unroll
        for (int ks = 0; ks < 4; ++ks)
            afr[ks] = (mr < N) ? *(const bf16x8*)&A[(size_t)mr * HDIM + ks * 32 + qa * 8]
                               : azero;
        f32x4 acc[8];
        #pragma unroll
        for (int nf = 0; nf < 8; ++nf)
            #pragma unroll
            for (int j = 0; j < 4; ++j) acc[nf][j] = 0.f;
        #pragma unroll
        for (int ks = 0; ks < 4; ++ks)
            #pragma unroll
            for (int nf = 0; nf < 8; ++nf)
                acc[nf] = __builtin_amdgcn_mfma_f32_16x16x32_bf16(afr[ks], bfr[ks][nf], acc[nf], 0, 0, 0);
        #pragma unroll
        for (int nf = 0; nf < 8; ++nf) {
            #pragma unroll
            for (int r = 0; r < 4; ++r) {
                int row = m0 + qa * 4 + r;
                if (row < N) {
                    float v = acc[nf][r] + bi[nf];
                    if (MODE == 0) v = fmaxf(v, 0.f);
                    else           v = fmaxf(fmaf(gg[nf] * v, INVSTD, be[nf]), 0.f);
                    out[(size_t)row * HDIM + nf * 16 + ra] = (ushort_t)f2bf(v);
                }
            }
        }
    }
}

// ------------- pooling: segmented reduction over sorted batch (bf16 in) -------------
#define PCHUNK 256
#define PWIN 4
__global__ __launch_bounds__(256) void k_pool2(const ushort_t* __restrict__ hb,
                                               const int* __restrict__ batch,
                                               float* pooled, int N) {
    __shared__ float acc[PWIN][HDIM];
    int n0 = blockIdx.x * PCHUNK;
    if (n0 >= N) return;
    int n1 = min(n0 + PCHUNK, N);
    int g0 = batch[n0];
    int g1 = batch[n1 - 1];
    for (int i = threadIdx.x; i < PWIN * HDIM; i += 256) ((float*)acc)[i] = 0.f;
    __syncthreads();

    int grp = threadIdx.x >> 5;
    int q = threadIdx.x & 31;
    float4 racc = make_float4(0.f, 0.f, 0.f, 0.f);
    int gcur = g0;
    for (int n = n0 + grp; n < n1; n += 8) {
        int g = batch[n];
        if (g != gcur) {
            int w = gcur - g0;
            float* p = (w < PWIN) ? &acc[w][q * 4] : (pooled + gcur * HDIM + q * 4);
            atomicAdd(p + 0, racc.x); atomicAdd(p + 1, racc.y);
            atomicAdd(p + 2, racc.z); atomicAdd(p + 3, racc.w);
            racc = make_float4(0.f, 0.f, 0.f, 0.f);
            gcur = g;
        }
        uint2 u = ((const uint2*)(hb + (size_t)n * HDIM))[q];
        racc.x += bf2f(u.x & 0xFFFFu);
        racc.y += bf2f(u.x >> 16);
        racc.z += bf2f(u.y & 0xFFFFu);
        racc.w += bf2f(u.y >> 16);
    }
    {
        int w = gcur - g0;
        float* p = (w < PWIN) ? &acc[w][q * 4] : (pooled + gcur * HDIM + q * 4);
        atomicAdd(p + 0, racc.x); atomicAdd(p + 1, racc.y);
        atomicAdd(p + 2, racc.z); atomicAdd(p + 3, racc.w);
    }
    __syncthreads();

    int span = min(g1 - g0 + 1, PWIN);
    for (int i = threadIdx.x; i < span * HDIM; i += 256) {
        int w = i >> 7, f = i & 127;
        float v = acc[w][f];
        if (v != 0.f) atomicAdd(pooled + (g0 + w) * HDIM + f, v);
    }
}

__global__ void k_count(const int* __restrict__ batch, float* cnt, int N) {
    int g = threadIdx.x;
    if (g >= NGRAPH) return;
    int lo = 0, hi = N;
    while (lo < hi) { int m = (lo + hi) >> 1; if (batch[m] < g) lo = m + 1; else hi = m; }
    int lo2 = lo, hi2 = N;
    while (lo2 < hi2) { int m = (lo2 + hi2) >> 1; if (batch[m] < g + 1) lo2 = m + 1; else hi2 = m; }
    cnt[g] = (float)(lo2 - lo);
}

// ------------- classifier -------------
__global__ void k_classify(const float* __restrict__ pooled, const float* __restrict__ cnt,
                           const float* __restrict__ cw1, const float* __restrict__ cb1,
                           const float* __restrict__ cw2, const float* __restrict__ cb2,
                           float* __restrict__ out) {
    __shared__ float p[HDIM];
    int g = blockIdx.x, j = threadIdx.x;
    float c = fmaxf(cnt[g], 1.f);
    p[j]      = pooled[g * HDIM + j] / c;
    p[j + 64] = pooled[g * HDIM + j + 64] / c;
    __syncthreads();
    float acc = cb1[j];
    #pragma unroll 4
    for (int k = 0; k < HDIM; ++k) acc = fmaf(p[k], cw1[k * 64 + j], acc);
    acc = fmaxf(acc, 0.f);
    float v = acc * cw2[j];
    #pragma unroll
    for (int off = 32; off > 0; off >>= 1) v += __shfl_down(v, off, 64);
    if (j == 0) out[g] = 1.f / (1.f + expf(-(v + cb2[0])));
}

static inline size_t align_up(size_t v, size_t a) { return (v + a - 1) & ~(a - 1); }

extern "C" void kernel_launch(void* const* d_in, const int* in_sizes, int n_in,
                              void* d_out, int out_size, void* d_ws, size_t ws_size,
                              hipStream_t stream) {
    const float* x      = (const float*)d_in[0];
    const int*   ei     = (const int*)d_in[1];
    const float* eattr  = (const float*)d_in[2];
    const int*   batch  = (const int*)d_in[3];
    const float* enc_w  = (const float*)d_in[4];
    const float* enc_b  = (const float*)d_in[5];
    const float* eenc_w = (const float*)d_in[6];
    const float* eenc_b = (const float*)d_in[7];
    const float* eps    = (const float*)d_in[8];
    const float* w1     = (const float*)d_in[9];
    const float* b1     = (const float*)d_in[10];
    const float* w2     = (const float*)d_in[11];
    const float* b2     = (const float*)d_in[12];
    const float* gamma  = (const float*)d_in[13];
    const float* beta   = (const float*)d_in[14];
    const float* cw1    = (const float*)d_in[15];
    const float* cb1    = (const float*)d_in[16];
    const float* cw2    = (const float*)d_in[17];
    const float* cb2    = (const float*)d_in[18];

    int N = in_sizes[0];          // 100000
    int E = in_sizes[2];          // 1600000

    char* wsb = (char*)d_ws;
    size_t off = 0;
    ushort_t* hb  = (ushort_t*)(wsb + off); off = align_up(off + (size_t)N * HDIM * 2, 256);
    ushort_t* zb  = (ushort_t*)(wsb + off); off = align_up(off + (size_t)N * HDIM * 2, 256);
    float* pooled = (float*)(wsb + off);    off = align_up(off + NGRAPH * HDIM * 4, 256);
    float* cnt    = (float*)(wsb + off);    off = align_up(off + NGRAPH * 4, 256);
    int*   deg    = (int*)(wsb + off);      off = align_up(off + (size_t)N * 4, 256);
    int*   rs     = (int*)(wsb + off);      off = align_up(off + (size_t)(N + 1) * 4, 256);
    int*   rank_  = (int*)(wsb + off);      off = align_up(off + (size_t)E * 4, 256);
    int*   bsum   = (int*)(wsb + off);      off = align_up(off + 2048 * 4, 256);
    int2*  epack  = (int2*)(wsb + off);     off = align_up(off + (size_t)E * 8, 256);

    int nb = (N + 255) / 256;
    int eb_blocks = (E + 255) / 256;

    // CSR build
    hipMemsetAsync(deg, 0, (size_t)N * 4, stream);
    k_hist<<<eb_blocks, 256, 0, stream>>>(ei, deg, rank_, E);
    k_scan1<<<nb, 256, 0, stream>>>(deg, rs, bsum, N);
    k_scan2<<<1, 512, 0, stream>>>(bsum, nb);
    k_scan3<<<(N + 256) / 256, 256, 0, stream>>>(rs, bsum, N, E);
    k_scatter<<<eb_blocks, 256, 0, stream>>>(ei, eattr, rs, rank_, epack, E);

    hipMemsetAsync(pooled, 0, (NGRAPH * HDIM + NGRAPH) * sizeof(float), stream);
    k_encode<<<2048, 256, 0, stream>>>(x, enc_w, enc_b, hb, N);

    int gblocks = (N + 127) / 128;
    int ablocks = (N * 64 + 255) / 256;
    for (int l = 0; l < 2; ++l) {
        k_agg<<<ablocks, 256, 0, stream>>>(hb, rs, epack, eenc_w, eenc_b, eps + l, zb, N);
        k_gemm<0><<<gblocks, 256, 0, stream>>>(zb, w1 + (size_t)l * HDIM * HDIM,
                                               b1 + l * HDIM, nullptr, nullptr, zb, N);
        k_gemm<1><<<gblocks, 256, 0, stream>>>(zb, w2 + (size_t)l * HDIM * HDIM,
                                               b2 + l * HDIM, gamma + l * HDIM, beta + l * HDIM,
                                               hb, N);
    }

    k_pool2<<<(N + PCHUNK - 1) / PCHUNK, 256, 0, stream>>>(hb, batch, pooled, N);
    k_count<<<1, 64, 0, stream>>>(batch, cnt, N);
    k_classify<<<NGRAPH, 64, 0, stream>>>(pooled, cnt, cw1, cb1, cw2, cb2, (float*)d_out);
}